// Round 3
// baseline (236.558 us; speedup 1.0000x reference)
//
#include <hip/hip_runtime.h>

#define NN 50000
#define FIN 128
#define HC 256
#define NH 8
#define NE 800000
#define WROW 136        // padded LDS row (shorts); rows 16B-aligned
#define FILLB 782       // fill blocks first: 782 * 1024 edges >= NE (4 edges/thread)
#define GEMMB 782       // 391 row-blocks x 2 column halves (128 cols each)
#define NBLK1 1564      // 782 fill + 782 gemm
#define OVFCAP 131072
#define CSTR 16         // cnt stride in ints: one 64B line per counter

typedef __attribute__((ext_vector_type(8))) short short8;
typedef __attribute__((ext_vector_type(4))) short short4v;
typedef __attribute__((ext_vector_type(4))) float floatx4;

__device__ __forceinline__ float bf2f(unsigned short u) {
    union { unsigned int i; float f; } v; v.i = ((unsigned int)u) << 16; return v.f;
}
__device__ __forceinline__ unsigned short f2bf(float f) {
    union { float f; unsigned int i; } v; v.f = f;
    unsigned int r = v.i + 0x7fffu + ((v.i >> 16) & 1u);
    return (unsigned short)(r >> 16);
}
__device__ __forceinline__ float lrelu(float x) { return x > 0.f ? x : 0.2f * x; }
__device__ __forceinline__ float ldf(const void* p, int f32, long long i) {
    return f32 ? ((const float*)p)[i] : bf2f(((const unsigned short*)p)[i]);
}
__device__ __forceinline__ int lde(const int* ei, int i64, long long i) {
    return i64 ? (int)((const long long*)ei)[i] : ei[i];
}
__device__ __forceinline__ float sel8(const float s[2][4], int t2, int rr) {
    float a0 = t2 ? s[1][0] : s[0][0];
    float a1 = t2 ? s[1][1] : s[0][1];
    float a2 = t2 ? s[1][2] : s[0][2];
    float a3 = t2 ? s[1][3] : s[0][3];
    return (rr == 0) ? a0 : ((rr == 1) ? a1 : ((rr == 2) ? a2 : a3));
}
// bf16 pair unpack from one dword: low short = <<16, high short = mask (no shift)
__device__ __forceinline__ float blo(unsigned int u) {
    union { unsigned int i; float f; } v; v.i = u << 16; return v.f;
}
__device__ __forceinline__ float bhi(unsigned int u) {
    union { unsigned int i; float f; } v; v.i = u & 0xFFFF0000u; return v.f;
}
__device__ __forceinline__ float bperm(int addr, float v) {
    return __uint_as_float((unsigned int)__builtin_amdgcn_ds_bpermute(addr, (int)__float_as_uint(v)));
}

// ---- K1: blocks < FILLB: bucket-fill, 4 edges/thread (4 independent far-atomic
//          chains -> 4x MLP); cnt padded to one 64B line per counter to kill
//          same-line far-atomic serialization (was 256 atomics/line).
//          blocks >= FILLB: MFMA GEMM + attention scores, column-split
//          (128 rows x 128 cols per block, LDS 34,816 B -> 4 blocks/CU).
__global__ __launch_bounds__(256) void k_front(
        const void* __restrict__ x, const int* __restrict__ ei,
        const void* __restrict__ dpm, const void* __restrict__ W,
        const void* __restrict__ as_, const void* __restrict__ ad_,
        int* __restrict__ flags, unsigned short* __restrict__ h,
        float* __restrict__ a_src, float* __restrict__ a_dst,
        int* __restrict__ cnt, int* __restrict__ ovfcnt,
        unsigned int* __restrict__ bucket, int2* __restrict__ ovf,
        int cap, int capl2) {
    __shared__ unsigned short lwt[128 * WROW];   // 34,816 B
    __shared__ int s_bad, s_nz;
    const int tid = threadIdx.x;
    const int b = blockIdx.x;

    // dtype probe (local per block; leading words are L2-hot)
    if (tid == 0) { s_bad = 0; s_nz = 0; }
    __syncthreads();
    {
        unsigned int wv = ((const unsigned int*)dpm)[tid];   // fp32 dp_mask words: 0 or 2.5f
        if (wv != 0u && wv != 0x40200000u) atomicAdd(&s_bad, 1);
        if (((const unsigned int*)ei)[2 * tid + 1] != 0u) atomicAdd(&s_nz, 1);
    }
    __syncthreads();
    const int f32 = (s_bad == 0) ? 1 : 0;
    const int i64 = (s_nz == 0) ? 1 : 0;
    if (b == 0 && tid == 0) { flags[0] = f32; flags[1] = i64; }

    if (b < FILLB) {
        // ---- bucket fill: 4 edges per thread, independent chains ----
        const long long e0 = (long long)b * 1024 + tid;
        #pragma unroll
        for (int i = 0; i < 4; i++) {
            long long e = e0 + i * 256;
            if (e < NE) {
                int dst = lde(ei, i64, e);
                int src = lde(ei, i64, (long long)NE + e);
                unsigned int msk = 0;
                if (f32) {
                    const floatx4* dp = (const floatx4*)((const float*)dpm + e * 8);
                    floatx4 d0 = dp[0], d1 = dp[1];
                    #pragma unroll
                    for (int j = 0; j < 4; j++) {
                        msk |= (d0[j] != 0.f ? 1u : 0u) << j;
                        msk |= (d1[j] != 0.f ? 1u : 0u) << (4 + j);
                    }
                } else {
                    short8 dd = *(const short8*)((const unsigned short*)dpm + e * 8);
                    #pragma unroll
                    for (int j = 0; j < 8; j++) msk |= (dd[j] != 0 ? 1u : 0u) << j;
                }
                unsigned int entry = (unsigned int)src | (msk << 16);
                int pos = atomicAdd(&cnt[dst * CSTR], 1);
                if (pos < cap) bucket[((long long)dst << capl2) + pos] = entry;
                else {
                    int op = atomicAdd(ovfcnt, 1);
                    if (op < OVFCAP) ovf[op] = make_int2(dst, (int)entry);
                }
            }
        }
    } else {
        const int bb = b - FILLB;
        const int ch = bb & 1;         // column half: global cols ch*128 .. +127
        const int rb = bb >> 1;        // row block
        // ---- stage W^T half into LDS: two threads per column, 64 k's each; coalesced ----
        {
            const int lcol = tid & 127;
            const int col = ch * 128 + lcol;
            const int k0 = (tid >> 7) * 64;
            if (f32) {
                const float* wp = (const float*)W + col;
                for (int k = k0; k < k0 + 64; k++) lwt[lcol * WROW + k] = f2bf(wp[(long long)k * HC]);
            } else {
                const unsigned short* wp = (const unsigned short*)W + col;
                for (int k = k0; k < k0 + 64; k++) lwt[lcol * WROW + k] = wp[(long long)k * HC];
            }
        }
        __syncthreads();

        const int lane = tid & 63;
        const int wave = tid >> 6;
        const int lrow = lane & 15;
        const int quad = lane >> 4;
        const int row0w = rb * 128 + wave * 32;

        short8 a[2][4];
        #pragma unroll
        for (int t = 0; t < 2; t++)
            #pragma unroll
            for (int q = 0; q < 4; q++)
                #pragma unroll
                for (int j = 0; j < 8; j++) a[t][q][j] = 0;

        #pragma unroll
        for (int t = 0; t < 2; t++) {
            int row = row0w + t * 16 + lrow;
            if (row < NN) {
                if (f32) {
                    const float* xp = (const float*)x + (long long)row * FIN + quad * 8;
                    #pragma unroll
                    for (int q = 0; q < 4; q++) {
                        floatx4 u0 = *(const floatx4*)(xp + q * 32);
                        floatx4 u1 = *(const floatx4*)(xp + q * 32 + 4);
                        #pragma unroll
                        for (int j = 0; j < 4; j++) {
                            a[t][q][j]     = (short)f2bf(u0[j]);
                            a[t][q][j + 4] = (short)f2bf(u1[j]);
                        }
                    }
                } else {
                    const unsigned short* xp = (const unsigned short*)x + (long long)row * FIN + quad * 8;
                    #pragma unroll
                    for (int q = 0; q < 4; q++) a[t][q] = *(const short8*)(xp + q * 32);
                }
            }
        }

        float sS[2][4], sD[2][4];
        #pragma unroll 4
        for (int ct = 0; ct < 8; ct++) {
            if ((ct & 1) == 0) {
                #pragma unroll
                for (int t = 0; t < 2; t++)
                    #pragma unroll
                    for (int r = 0; r < 4; r++) { sS[t][r] = 0.f; sD[t][r] = 0.f; }
            }
            floatx4 acc0 = {0.f, 0.f, 0.f, 0.f};
            floatx4 acc1 = {0.f, 0.f, 0.f, 0.f};
            const unsigned short* wp = lwt + (ct * 16 + lrow) * WROW + quad * 8;
            #pragma unroll
            for (int q = 0; q < 4; q++) {
                short8 bb2 = *(const short8*)(wp + q * 32);
                acc0 = __builtin_amdgcn_mfma_f32_16x16x32_bf16(a[0][q], bb2, acc0, 0, 0, 0);
                acc1 = __builtin_amdgcn_mfma_f32_16x16x32_bf16(a[1][q], bb2, acc1, 0, 0, 0);
            }
            const int gcol = ch * 128 + ct * 16 + lrow;
            // C/D: col = lane&15, row = quad*4 + reg
            #pragma unroll
            for (int r = 0; r < 4; r++) {
                int orow = row0w + quad * 4 + r;
                if (orow < NN) h[(long long)orow * HC + gcol] = f2bf(acc0[r]);
                int orow1 = orow + 16;
                if (orow1 < NN) h[(long long)orow1 * HC + gcol] = f2bf(acc1[r]);
            }
            float tS = ldf(as_, f32, gcol);
            float tD = ldf(ad_, f32, gcol);
            #pragma unroll
            for (int r = 0; r < 4; r++) {
                sS[0][r] += acc0[r] * tS;  sS[1][r] += acc1[r] * tS;
                sD[0][r] += acc0[r] * tD;  sD[1][r] += acc1[r] * tD;
            }
            if (ct & 1) {   // head (ch*4 + ct>>1) complete: reduce over 16-lane col group
                #pragma unroll
                for (int m = 1; m <= 8; m <<= 1)
                    #pragma unroll
                    for (int t = 0; t < 2; t++)
                        #pragma unroll
                        for (int r = 0; r < 4; r++) {
                            sS[t][r] += __shfl_xor(sS[t][r], m);
                            sD[t][r] += __shfl_xor(sD[t][r], m);
                        }
                int hd = ch * 4 + (ct >> 1);
                if (lrow < 8) {
                    int t2 = lrow >> 2, rr = lrow & 3;
                    int row = row0w + t2 * 16 + quad * 4 + rr;
                    if (row < NN) a_src[row * NH + hd] = sel8(sS, t2, rr);
                } else {
                    int lr = lrow - 8;
                    int t2 = lr >> 2, rr = lr & 3;
                    int row = row0w + t2 * 16 + quad * 4 + rr;
                    if (row < NN) a_dst[row * NH + hd] = sel8(sD, t2, rr);
                }
            }
        }
    }
}

// ---- K2: single-pass softmax + aggregation, one wave per node.
//      v3: h-row gathers issued IMMEDIATELY after the uniform chunk loads
//      (unconditionally; overlap a_src gather + exp + bperm latency), ue via
//      cndmask select tree from uniform u's (no per-lane bucket gather),
//      NaN-safe gating of dropped/padded rows via cndmask-zeroed operands.
__global__ __launch_bounds__(256) void k_aggr(
        const int* __restrict__ cnt, const int* __restrict__ ovfcnt,
        const unsigned int* __restrict__ bucket, const int2* __restrict__ ovf,
        const float* __restrict__ a_src, const float* __restrict__ a_dst,
        const unsigned short* __restrict__ h, const void* __restrict__ dps,
        const int* __restrict__ flags, const void* __restrict__ bs_,
        void* __restrict__ out, int cap, int capl2) {
    int node = blockIdx.x * 4 + (threadIdx.x >> 6);
    int lane = threadIdx.x & 63;
    if (node >= NN) return;
    const int unode = __builtin_amdgcn_readfirstlane(node);   // wave-uniform -> SGPR
    const int f32 = flags[0];
    int novf = *ovfcnt; novf = novf > OVFCAP ? OVFCAP : novf;
    int mn = cnt[unode * CSTR]; mn = mn < cap ? mn : cap;
    const unsigned int* __restrict__ bp = bucket + ((long long)unode << capl2);

    const int hh = lane >> 3;              // head owned by this lane (producer+consumer)
    const int e8 = lane & 7;               // producer's edge slot within chunk
    const int badr = (lane & 56) << 2;     // bpermute byte base of this head group
    const int cb = lane * 4;               // channel base within h-row (shorts)
    const float adst = a_dst[unode * NH + hh];

    float dnp = 0.f;                       // producer-side partial denominator
    float acc0 = 0.f, acc1 = 0.f, acc2 = 0.f, acc3 = 0.f;

    for (int j = 0; j < mn; j += 8) {
        // chunk entries at wave-uniform addresses (scalar loads)
        unsigned int u0 = bp[j + 0], u1 = bp[j + 1], u2 = bp[j + 2], u3 = bp[j + 3],
                     u4 = bp[j + 4], u5 = bp[j + 5], u6 = bp[j + 6], u7 = bp[j + 7];

        // ---- issue h-row gathers NOW (SGPR base + lane offset); loads are
        //      unconditional so they fly under the softmax chain; garbage rows
        //      (dropped/padded) are zeroed before the MAC via cndmask.
        #define GATH(K) \
            const unsigned short* hp##K = h + \
                (((long long)(__builtin_amdgcn_readfirstlane((int)u##K) & 0xFFFF)) << 8); \
            uint2 v##K = *(const uint2*)(hp##K + cb);
        GATH(0) GATH(1) GATH(2) GATH(3) GATH(4) GATH(5) GATH(6) GATH(7)
        #undef GATH

        // ---- producer: one (edge,head) per lane; ue selected in-register
        unsigned int s0a = (e8 & 1) ? u1 : u0;
        unsigned int s1a = (e8 & 1) ? u3 : u2;
        unsigned int s2a = (e8 & 1) ? u5 : u4;
        unsigned int s3a = (e8 & 1) ? u7 : u6;
        unsigned int t0a = (e8 & 2) ? s1a : s0a;
        unsigned int t1a = (e8 & 2) ? s3a : s2a;
        unsigned int ue  = (e8 & 4) ? t1a : t0a;
        int idx = j + e8;
        int esrc = (int)(ue & 0xFFFFu);
        float al = a_src[esrc * NH + hh] + adst;
        float w = __expf(fmaxf(al, 0.2f * al));
        w = idx < mn ? w : 0.f;            // mask BEFORE use (kills inf/NaN garbage)
        dnp += w;
        float ws = ((ue >> (16 + hh)) & 1u) ? w : -w;   // sign carries dropout bit

        // ---- consumers: broadcast weight, gate operands, MAC
        #define CONS(K) { \
            float wv = bperm(badr + 4 * K, ws); \
            float p = fmaxf(wv, 0.f) * 2.5f; \
            unsigned int gx = wv > 0.f ? v##K.x : 0u; \
            unsigned int gy = wv > 0.f ? v##K.y : 0u; \
            acc0 = fmaf(p, blo(gx), acc0); acc1 = fmaf(p, bhi(gx), acc1); \
            acc2 = fmaf(p, blo(gy), acc2); acc3 = fmaf(p, bhi(gy), acc3); }
        CONS(0) CONS(1) CONS(2) CONS(3) CONS(4) CONS(5) CONS(6) CONS(7)
        #undef CONS
    }

    // reduce producer denominators across the 8 lanes of each head group
    dnp += __shfl_xor(dnp, 1);
    dnp += __shfl_xor(dnp, 2);
    dnp += __shfl_xor(dnp, 4);
    float dn = dnp;

    // overflow sweep (novf ~ 0 in practice; correct for any value)
    for (int i = 0; i < novf; i++) {
        int2 tv = ovf[i];
        if (tv.x == node) {
            unsigned int u = (unsigned int)tv.y;
            int src = (int)(u & 0xFFFFu);
            float w = __expf(lrelu(a_src[src * NH + hh] + adst));
            dn += w;
            if ((u >> (16 + hh)) & 1u) {
                uint2 hv = *(const uint2*)(h + ((long long)src << 8) + cb);
                float p = w * 2.5f;
                acc0 = fmaf(p, blo(hv.x), acc0); acc1 = fmaf(p, bhi(hv.x), acc1);
                acc2 = fmaf(p, blo(hv.y), acc2); acc3 = fmaf(p, bhi(hv.y), acc3);
            }
        }
    }
    { // self-loop
        float wS = __expf(lrelu(a_src[unode * NH + hh] + adst));
        dn += wS;
        float pS = wS * ldf(dps, f32, (long long)unode * NH + hh);
        uint2 hv = *(const uint2*)(h + ((long long)unode << 8) + cb);
        acc0 = fmaf(pS, blo(hv.x), acc0); acc1 = fmaf(pS, bhi(hv.x), acc1);
        acc2 = fmaf(pS, blo(hv.y), acc2); acc3 = fmaf(pS, bhi(hv.y), acc3);
    }
    float inv = 1.0f / dn;
    float b0 = ldf(bs_, f32, cb + 0), b1 = ldf(bs_, f32, cb + 1);
    float b2 = ldf(bs_, f32, cb + 2), b3 = ldf(bs_, f32, cb + 3);
    if (f32) {
        floatx4 o = {acc0 * inv + b0, acc1 * inv + b1, acc2 * inv + b2, acc3 * inv + b3};
        *(floatx4*)((float*)out + (long long)node * HC + cb) = o;
    } else {
        short4v o;
        o[0] = (short)f2bf(acc0 * inv + b0);
        o[1] = (short)f2bf(acc1 * inv + b1);
        o[2] = (short)f2bf(acc2 * inv + b2);
        o[3] = (short)f2bf(acc3 * inv + b3);
        *(short4v*)((unsigned short*)out + (long long)node * HC + cb) = o;
    }
}

extern "C" void kernel_launch(void* const* d_in, const int* in_sizes, int n_in,
                              void* d_out, int out_size, void* d_ws, size_t ws_size,
                              hipStream_t stream) {
    const void* x       = d_in[0];
    const int*  ei      = (const int*)d_in[1];
    const void* dp_mask = d_in[2];
    const void* dp_self = d_in[3];
    const void* W       = d_in[4];
    const void* att_s   = d_in[5];
    const void* att_d   = d_in[6];
    const void* bias    = d_in[7];

    char* w = (char*)d_ws;
    unsigned short* h      = (unsigned short*)(w + 0);             // 25,600,000
    float*          a_src  = (float*)(w + 25600000);               //  1,600,000
    float*          a_dst  = (float*)(w + 27200000);               //  1,600,000
    int*            cnt    = (int*)(w + 28800000);                 //  3,200,000 (64B-strided)
    int*            ovfcnt = (int*)(w + 32000000);                 //          4
    int*            flags  = (int*)(w + 32000064);                 //          8
    int2*           ovf    = (int2*)(w + 32000960);                //  1,048,576
    unsigned int*   bucket = (unsigned int*)(w + 33049536);        //  cap*200,000

    // 512 B slack: k_aggr chunk reads may run up to 7 entries past the last
    // node's row (values masked, never dereferenced as large offsets).
    long long avail = (long long)ws_size - 33049536LL - 512LL;
    int cap = 64, capl2 = 6;
    while (cap > 4 && (long long)cap * 200000LL > avail) { cap >>= 1; capl2--; }

    // zero cnt (64B-strided) + ovfcnt (+flags; flags rewritten by k_front
    // before k_aggr reads them)
    hipMemsetAsync(cnt, 0, 3200128, stream);
    k_front<<<NBLK1, 256, 0, stream>>>(x, ei, dp_mask, W, att_s, att_d,
                                       flags, h, a_src, a_dst, cnt, ovfcnt, bucket, ovf,
                                       cap, capl2);
    k_aggr<<<NN / 4, 256, 0, stream>>>(cnt, ovfcnt, bucket, ovf, a_src, a_dst, h,
                                       dp_self, flags, bias, d_out, cap, capl2);
}

// Round 4
// 230.029 us; speedup vs baseline: 1.0284x; 1.0284x over previous
//
#include <hip/hip_runtime.h>

#define NN 50000
#define FIN 128
#define HC 256
#define NH 8
#define NE 800000
#define WROW 136        // padded LDS row (shorts); rows 16B-aligned
#define FILLB 3125      // 3125*256 == NE exactly, 1 edge/thread
#define GEMMB 391       // 391*128 rows >= NN; each block does BOTH column halves
#define OVFCAP 131072

typedef __attribute__((ext_vector_type(8))) short short8;
typedef __attribute__((ext_vector_type(4))) short short4v;
typedef __attribute__((ext_vector_type(4))) float floatx4;

__device__ __forceinline__ float bf2f(unsigned short u) {
    union { unsigned int i; float f; } v; v.i = ((unsigned int)u) << 16; return v.f;
}
__device__ __forceinline__ unsigned short f2bf(float f) {
    union { float f; unsigned int i; } v; v.f = f;
    unsigned int r = v.i + 0x7fffu + ((v.i >> 16) & 1u);
    return (unsigned short)(r >> 16);
}
__device__ __forceinline__ float lrelu(float x) { return x > 0.f ? x : 0.2f * x; }
__device__ __forceinline__ float ldf(const void* p, int f32, long long i) {
    return f32 ? ((const float*)p)[i] : bf2f(((const unsigned short*)p)[i]);
}
__device__ __forceinline__ int lde(const int* ei, int i64, long long i) {
    return i64 ? (int)((const long long*)ei)[i] : ei[i];
}
__device__ __forceinline__ float sel8(const float s[2][4], int t2, int rr) {
    float a0 = t2 ? s[1][0] : s[0][0];
    float a1 = t2 ? s[1][1] : s[0][1];
    float a2 = t2 ? s[1][2] : s[0][2];
    float a3 = t2 ? s[1][3] : s[0][3];
    return (rr == 0) ? a0 : ((rr == 1) ? a1 : ((rr == 2) ? a2 : a3));
}
// bf16 pair unpack from one dword: low short = <<16, high short = mask (no shift)
__device__ __forceinline__ float blo(unsigned int u) {
    union { unsigned int i; float f; } v; v.i = u << 16; return v.f;
}
__device__ __forceinline__ float bhi(unsigned int u) {
    union { unsigned int i; float f; } v; v.i = u & 0xFFFF0000u; return v.f;
}
__device__ __forceinline__ float bperm(int addr, float v) {
    return __uint_as_float((unsigned int)__builtin_amdgcn_ds_bpermute(addr, (int)__float_as_uint(v)));
}

// ---- K_fill: bucket fill, 1 edge/thread, dense cnt (R2-proven shape),
//      its own dispatch for per-phase rocprof attribution.
__global__ __launch_bounds__(256) void k_fill(
        const int* __restrict__ ei, const void* __restrict__ dpm,
        int* __restrict__ flags, int* __restrict__ cnt, int* __restrict__ ovfcnt,
        unsigned int* __restrict__ bucket, int2* __restrict__ ovf,
        int cap, int capl2) {
    __shared__ int s_bad, s_nz;
    const int tid = threadIdx.x;
    const int b = blockIdx.x;
    if (tid == 0) { s_bad = 0; s_nz = 0; }
    __syncthreads();
    {
        unsigned int wv = ((const unsigned int*)dpm)[tid];   // fp32 dp_mask words: 0 or 2.5f
        if (wv != 0u && wv != 0x40200000u) atomicAdd(&s_bad, 1);
        if (((const unsigned int*)ei)[2 * tid + 1] != 0u) atomicAdd(&s_nz, 1);
    }
    __syncthreads();
    const int f32 = (s_bad == 0) ? 1 : 0;
    const int i64 = (s_nz == 0) ? 1 : 0;
    if (b == 0 && tid == 0) { flags[0] = f32; flags[1] = i64; }

    const long long e = (long long)b * 256 + tid;   // < NE by construction
    int dst = lde(ei, i64, e);
    int src = lde(ei, i64, (long long)NE + e);
    unsigned int msk = 0;
    if (f32) {
        const floatx4* dp = (const floatx4*)((const float*)dpm + e * 8);
        floatx4 d0 = dp[0], d1 = dp[1];
        #pragma unroll
        for (int j = 0; j < 4; j++) {
            msk |= (d0[j] != 0.f ? 1u : 0u) << j;
            msk |= (d1[j] != 0.f ? 1u : 0u) << (4 + j);
        }
    } else {
        short8 dd = *(const short8*)((const unsigned short*)dpm + e * 8);
        #pragma unroll
        for (int j = 0; j < 8; j++) msk |= (dd[j] != 0 ? 1u : 0u) << j;
    }
    unsigned int entry = (unsigned int)src | (msk << 16);
    int pos = atomicAdd(&cnt[dst], 1);
    if (pos < cap) bucket[((long long)dst << capl2) + pos] = entry;
    else {
        int op = atomicAdd(ovfcnt, 1);
        if (op < OVFCAP) ovf[op] = make_int2(dst, (int)entry);
    }
}

// ---- K_gemm: MFMA GEMM + attention scores. Each block: 128 rows x 256 cols,
//      x loaded ONCE into registers; W staged per 128-col half into a 34,816 B
//      LDS buffer (4 blocks/CU), two sequential halves.
__global__ __launch_bounds__(256) void k_gemm(
        const void* __restrict__ x, const void* __restrict__ dpm,
        const void* __restrict__ W,
        const void* __restrict__ as_, const void* __restrict__ ad_,
        unsigned short* __restrict__ h,
        float* __restrict__ a_src, float* __restrict__ a_dst) {
    __shared__ unsigned short lwt[128 * WROW];   // 34,816 B
    __shared__ int s_bad;
    const int tid = threadIdx.x;
    const int b = blockIdx.x;
    if (tid == 0) s_bad = 0;
    __syncthreads();
    {
        unsigned int wv = ((const unsigned int*)dpm)[tid];
        if (wv != 0u && wv != 0x40200000u) atomicAdd(&s_bad, 1);
    }
    __syncthreads();
    const int f32 = (s_bad == 0) ? 1 : 0;

    const int lane = tid & 63;
    const int wave = tid >> 6;
    const int lrow = lane & 15;
    const int quad = lane >> 4;
    const int row0w = b * 128 + wave * 32;

    // ---- load x rows once (bf16 fragments in registers for both halves) ----
    short8 a[2][4];
    #pragma unroll
    for (int t = 0; t < 2; t++)
        #pragma unroll
        for (int q = 0; q < 4; q++)
            #pragma unroll
            for (int j = 0; j < 8; j++) a[t][q][j] = 0;

    #pragma unroll
    for (int t = 0; t < 2; t++) {
        int row = row0w + t * 16 + lrow;
        if (row < NN) {
            if (f32) {
                const float* xp = (const float*)x + (long long)row * FIN + quad * 8;
                #pragma unroll
                for (int q = 0; q < 4; q++) {
                    floatx4 u0 = *(const floatx4*)(xp + q * 32);
                    floatx4 u1 = *(const floatx4*)(xp + q * 32 + 4);
                    #pragma unroll
                    for (int j = 0; j < 4; j++) {
                        a[t][q][j]     = (short)f2bf(u0[j]);
                        a[t][q][j + 4] = (short)f2bf(u1[j]);
                    }
                }
            } else {
                const unsigned short* xp = (const unsigned short*)x + (long long)row * FIN + quad * 8;
                #pragma unroll
                for (int q = 0; q < 4; q++) a[t][q] = *(const short8*)(xp + q * 32);
            }
        }
    }

    #pragma unroll
    for (int ch = 0; ch < 2; ch++) {
        if (ch) __syncthreads();           // all reads of previous half done
        // ---- stage W^T half: two threads per column, 64 k's each; coalesced ----
        {
            const int lcol = tid & 127;
            const int col = ch * 128 + lcol;
            const int k0 = (tid >> 7) * 64;
            if (f32) {
                const float* wp = (const float*)W + col;
                for (int k = k0; k < k0 + 64; k++) lwt[lcol * WROW + k] = f2bf(wp[(long long)k * HC]);
            } else {
                const unsigned short* wp = (const unsigned short*)W + col;
                for (int k = k0; k < k0 + 64; k++) lwt[lcol * WROW + k] = wp[(long long)k * HC];
            }
        }
        __syncthreads();

        float sS[2][4], sD[2][4];
        #pragma unroll 4
        for (int ct = 0; ct < 8; ct++) {
            if ((ct & 1) == 0) {
                #pragma unroll
                for (int t = 0; t < 2; t++)
                    #pragma unroll
                    for (int r = 0; r < 4; r++) { sS[t][r] = 0.f; sD[t][r] = 0.f; }
            }
            floatx4 acc0 = {0.f, 0.f, 0.f, 0.f};
            floatx4 acc1 = {0.f, 0.f, 0.f, 0.f};
            const unsigned short* wp = lwt + (ct * 16 + lrow) * WROW + quad * 8;
            #pragma unroll
            for (int q = 0; q < 4; q++) {
                short8 bb = *(const short8*)(wp + q * 32);
                acc0 = __builtin_amdgcn_mfma_f32_16x16x32_bf16(a[0][q], bb, acc0, 0, 0, 0);
                acc1 = __builtin_amdgcn_mfma_f32_16x16x32_bf16(a[1][q], bb, acc1, 0, 0, 0);
            }
            const int gcol = ch * 128 + ct * 16 + lrow;
            // C/D: col = lane&15, row = quad*4 + reg
            #pragma unroll
            for (int r = 0; r < 4; r++) {
                int orow = row0w + quad * 4 + r;
                if (orow < NN) h[(long long)orow * HC + gcol] = f2bf(acc0[r]);
                int orow1 = orow + 16;
                if (orow1 < NN) h[(long long)orow1 * HC + gcol] = f2bf(acc1[r]);
            }
            float tS = ldf(as_, f32, gcol);
            float tD = ldf(ad_, f32, gcol);
            #pragma unroll
            for (int r = 0; r < 4; r++) {
                sS[0][r] += acc0[r] * tS;  sS[1][r] += acc1[r] * tS;
                sD[0][r] += acc0[r] * tD;  sD[1][r] += acc1[r] * tD;
            }
            if (ct & 1) {   // head (ch*4 + ct>>1) complete: reduce over 16-lane col group
                #pragma unroll
                for (int m = 1; m <= 8; m <<= 1)
                    #pragma unroll
                    for (int t = 0; t < 2; t++)
                        #pragma unroll
                        for (int r = 0; r < 4; r++) {
                            sS[t][r] += __shfl_xor(sS[t][r], m);
                            sD[t][r] += __shfl_xor(sD[t][r], m);
                        }
                int hd = ch * 4 + (ct >> 1);
                if (lrow < 8) {
                    int t2 = lrow >> 2, rr = lrow & 3;
                    int row = row0w + t2 * 16 + quad * 4 + rr;
                    if (row < NN) a_src[row * NH + hd] = sel8(sS, t2, rr);
                } else {
                    int lr = lrow - 8;
                    int t2 = lr >> 2, rr = lr & 3;
                    int row = row0w + t2 * 16 + quad * 4 + rr;
                    if (row < NN) a_dst[row * NH + hd] = sel8(sD, t2, rr);
                }
            }
        }
    }
}

// ---- K2: single-pass softmax + aggregation, one wave per node (v2, proven).
//      producer/consumer wave split — lane L computes exp() for exactly one
//      (edge L&7, head L>>3) per 8-edge chunk; dropout bit in the SIGN of the
//      broadcast weight; bucket entries read at wave-uniform addresses;
//      h-gathers SGPR-base + lane-offset; no scalar tail loop.
__global__ __launch_bounds__(256) void k_aggr(
        const int* __restrict__ cnt, const int* __restrict__ ovfcnt,
        const unsigned int* __restrict__ bucket, const int2* __restrict__ ovf,
        const float* __restrict__ a_src, const float* __restrict__ a_dst,
        const unsigned short* __restrict__ h, const void* __restrict__ dps,
        const int* __restrict__ flags, const void* __restrict__ bs_,
        void* __restrict__ out, int cap, int capl2) {
    int node = blockIdx.x * 4 + (threadIdx.x >> 6);
    int lane = threadIdx.x & 63;
    if (node >= NN) return;
    const int unode = __builtin_amdgcn_readfirstlane(node);   // wave-uniform -> SGPR
    const int f32 = flags[0];
    int novf = *ovfcnt; novf = novf > OVFCAP ? OVFCAP : novf;
    int mn = cnt[unode]; mn = mn < cap ? mn : cap;
    const unsigned int* __restrict__ bp = bucket + ((long long)unode << capl2);

    const int hh = lane >> 3;              // head owned by this lane (producer+consumer)
    const int e8 = lane & 7;               // producer's edge slot within chunk
    const int badr = (lane & 56) << 2;     // bpermute byte base of this head group
    const int cb = lane * 4;               // channel base within h-row (shorts)
    const float adst = a_dst[unode * NH + hh];

    float dnp = 0.f;                       // producer-side partial denominator
    float acc0 = 0.f, acc1 = 0.f, acc2 = 0.f, acc3 = 0.f;

    for (int j = 0; j < mn; j += 8) {
        // chunk entries at wave-uniform addresses (scalar-load friendly)
        unsigned int u0 = bp[j + 0], u1 = bp[j + 1], u2 = bp[j + 2], u3 = bp[j + 3],
                     u4 = bp[j + 4], u5 = bp[j + 5], u6 = bp[j + 6], u7 = bp[j + 7];

        // ---- producer: one (edge,head) per lane; clamp keeps loads in-bounds,
        //      padding lanes contribute w = 0.
        int idx = j + e8;
        int idxc = idx < mn ? idx : mn - 1;
        unsigned int ue = bp[idxc];
        int esrc = (int)(ue & 0xFFFFu);
        float al = a_src[esrc * NH + hh] + adst;
        float w = __expf(fmaxf(al, 0.2f * al));
        w = idx < mn ? w : 0.f;
        dnp += w;
        float ws = ((ue >> (16 + hh)) & 1u) ? w : -w;   // sign carries dropout bit

        // ---- consumers: broadcast weights (1 ds_bpermute per edge)
        #define GATW(K) float w##K = bperm(badr + 4 * K, ws);
        GATW(0) GATW(1) GATW(2) GATW(3) GATW(4) GATW(5) GATW(6) GATW(7)
        #undef GATW

        // gather h rows: SGPR base per edge + constant lane offset; batched loads
        #define GATH(K) \
            const unsigned short* hp##K = h + \
                (((long long)(__builtin_amdgcn_readfirstlane((int)u##K) & 0xFFFF)) << 8); \
            uint2 v##K = make_uint2(0u, 0u); \
            if (w##K > 0.f) v##K = *(const uint2*)(hp##K + cb);
        GATH(0) GATH(1) GATH(2) GATH(3) GATH(4) GATH(5) GATH(6) GATH(7)
        #undef GATH

        // unconditional MACs: dropped/padded edges have v == 0 (p*0 == 0)
        #define MACC(K) { float p = w##K * 2.5f; \
            acc0 = fmaf(p, blo(v##K.x), acc0); acc1 = fmaf(p, bhi(v##K.x), acc1); \
            acc2 = fmaf(p, blo(v##K.y), acc2); acc3 = fmaf(p, bhi(v##K.y), acc3); }
        MACC(0) MACC(1) MACC(2) MACC(3) MACC(4) MACC(5) MACC(6) MACC(7)
        #undef MACC
    }

    // reduce producer denominators across the 8 lanes of each head group
    dnp += __shfl_xor(dnp, 1);
    dnp += __shfl_xor(dnp, 2);
    dnp += __shfl_xor(dnp, 4);
    float dn = dnp;

    // overflow sweep (novf ~ 0 in practice; correct for any value)
    for (int i = 0; i < novf; i++) {
        int2 tv = ovf[i];
        if (tv.x == node) {
            unsigned int u = (unsigned int)tv.y;
            int src = (int)(u & 0xFFFFu);
            float w = __expf(lrelu(a_src[src * NH + hh] + adst));
            dn += w;
            if ((u >> (16 + hh)) & 1u) {
                uint2 hv = *(const uint2*)(h + ((long long)src << 8) + cb);
                float p = w * 2.5f;
                acc0 = fmaf(p, blo(hv.x), acc0); acc1 = fmaf(p, bhi(hv.x), acc1);
                acc2 = fmaf(p, blo(hv.y), acc2); acc3 = fmaf(p, bhi(hv.y), acc3);
            }
        }
    }
    { // self-loop
        float wS = __expf(lrelu(a_src[unode * NH + hh] + adst));
        dn += wS;
        float pS = wS * ldf(dps, f32, (long long)unode * NH + hh);
        uint2 hv = *(const uint2*)(h + ((long long)unode << 8) + cb);
        acc0 = fmaf(pS, blo(hv.x), acc0); acc1 = fmaf(pS, bhi(hv.x), acc1);
        acc2 = fmaf(pS, blo(hv.y), acc2); acc3 = fmaf(pS, bhi(hv.y), acc3);
    }
    float inv = 1.0f / dn;
    float b0 = ldf(bs_, f32, cb + 0), b1 = ldf(bs_, f32, cb + 1);
    float b2 = ldf(bs_, f32, cb + 2), b3 = ldf(bs_, f32, cb + 3);
    if (f32) {
        floatx4 o = {acc0 * inv + b0, acc1 * inv + b1, acc2 * inv + b2, acc3 * inv + b3};
        *(floatx4*)((float*)out + (long long)node * HC + cb) = o;
    } else {
        short4v o;
        o[0] = (short)f2bf(acc0 * inv + b0);
        o[1] = (short)f2bf(acc1 * inv + b1);
        o[2] = (short)f2bf(acc2 * inv + b2);
        o[3] = (short)f2bf(acc3 * inv + b3);
        *(short4v*)((unsigned short*)out + (long long)node * HC + cb) = o;
    }
}

extern "C" void kernel_launch(void* const* d_in, const int* in_sizes, int n_in,
                              void* d_out, int out_size, void* d_ws, size_t ws_size,
                              hipStream_t stream) {
    const void* x       = d_in[0];
    const int*  ei      = (const int*)d_in[1];
    const void* dp_mask = d_in[2];
    const void* dp_self = d_in[3];
    const void* W       = d_in[4];
    const void* att_s   = d_in[5];
    const void* att_d   = d_in[6];
    const void* bias    = d_in[7];

    char* w = (char*)d_ws;
    unsigned short* h      = (unsigned short*)(w + 0);             // 25,600,000
    float*          a_src  = (float*)(w + 25600000);               //  1,600,000
    float*          a_dst  = (float*)(w + 27200000);               //  1,600,000
    int*            cnt    = (int*)(w + 28800000);                 //    200,000
    int*            ovfcnt = (int*)(w + 29000000);                 //          4
    int*            flags  = (int*)(w + 29000064);                 //          8
    int2*           ovf    = (int2*)(w + 29000960);                //  1,048,576
    unsigned int*   bucket = (unsigned int*)(w + 30049536);        //  cap*200,000

    // 512 B slack: k_aggr chunk reads may run up to 7 entries past the last
    // node's bucket row (values masked, never used as addresses).
    long long avail = (long long)ws_size - 30049536LL - 512LL;
    int cap = 64, capl2 = 6;
    while (cap > 4 && (long long)cap * 200000LL > avail) { cap >>= 1; capl2--; }

    // zero cnt + ovfcnt (+flags; flags rewritten by k_fill before k_aggr reads)
    hipMemsetAsync(cnt, 0, 200960, stream);
    k_fill<<<FILLB, 256, 0, stream>>>(ei, dp_mask, flags, cnt, ovfcnt, bucket, ovf,
                                      cap, capl2);
    k_gemm<<<GEMMB, 256, 0, stream>>>(x, dp_mask, W, att_s, att_d, h, a_src, a_dst);
    k_aggr<<<NN / 4, 256, 0, stream>>>(cnt, ovfcnt, bucket, ovf, a_src, a_dst, h,
                                       dp_self, flags, bias, d_out, cap, capl2);
}

// Round 5
// 209.439 us; speedup vs baseline: 1.1295x; 1.0983x over previous
//
#include <hip/hip_runtime.h>

#define NN 50000
#define FIN 128
#define HC 256
#define NH 8
#define NE 800000
#define WROW 136        // padded LDS row (shorts); rows 16B-aligned
#define GEMMB 391       // 391*128 rows >= NN; each gemm block does BOTH column halves
#define NBLK1 3516      // 391 gemm + 3125 fill (3125*256 == NE exactly)
#define OVFCAP 131072

typedef __attribute__((ext_vector_type(8))) short short8;
typedef __attribute__((ext_vector_type(4))) short short4v;
typedef __attribute__((ext_vector_type(4))) float floatx4;

__device__ __forceinline__ float bf2f(unsigned short u) {
    union { unsigned int i; float f; } v; v.i = ((unsigned int)u) << 16; return v.f;
}
__device__ __forceinline__ unsigned short f2bf(float f) {
    union { float f; unsigned int i; } v; v.f = f;
    unsigned int r = v.i + 0x7fffu + ((v.i >> 16) & 1u);
    return (unsigned short)(r >> 16);
}
__device__ __forceinline__ float lrelu(float x) { return x > 0.f ? x : 0.2f * x; }
__device__ __forceinline__ float ldf(const void* p, int f32, long long i) {
    return f32 ? ((const float*)p)[i] : bf2f(((const unsigned short*)p)[i]);
}
__device__ __forceinline__ int lde(const int* ei, int i64, long long i) {
    return i64 ? (int)((const long long*)ei)[i] : ei[i];
}
__device__ __forceinline__ float sel8(const float s[2][4], int t2, int rr) {
    float a0 = t2 ? s[1][0] : s[0][0];
    float a1 = t2 ? s[1][1] : s[0][1];
    float a2 = t2 ? s[1][2] : s[0][2];
    float a3 = t2 ? s[1][3] : s[0][3];
    return (rr == 0) ? a0 : ((rr == 1) ? a1 : ((rr == 2) ? a2 : a3));
}
// bf16 pair unpack from one dword: low short = <<16, high short = mask (no shift)
__device__ __forceinline__ float blo(unsigned int u) {
    union { unsigned int i; float f; } v; v.i = u << 16; return v.f;
}
__device__ __forceinline__ float bhi(unsigned int u) {
    union { unsigned int i; float f; } v; v.i = u & 0xFFFF0000u; return v.f;
}
__device__ __forceinline__ float bperm(int addr, float v) {
    return __uint_as_float((unsigned int)__builtin_amdgcn_ds_bpermute(addr, (int)__float_as_uint(v)));
}

// ---- K1 (fused, R1-proven overlap): blocks < GEMMB: MFMA GEMM + attention
//      scores — x loaded ONCE into registers, W staged per 128-col half into a
//      34,816 B LDS buffer (4 blocks/CU), two sequential halves.
//      blocks >= GEMMB: bucket fill, 1 edge/thread (R2-proven shape).
__global__ __launch_bounds__(256) void k_front(
        const void* __restrict__ x, const int* __restrict__ ei,
        const void* __restrict__ dpm, const void* __restrict__ W,
        const void* __restrict__ as_, const void* __restrict__ ad_,
        int* __restrict__ flags, unsigned short* __restrict__ h,
        float* __restrict__ a_src, float* __restrict__ a_dst,
        int* __restrict__ cnt, int* __restrict__ ovfcnt,
        unsigned int* __restrict__ bucket, int2* __restrict__ ovf,
        int cap, int capl2) {
    __shared__ unsigned short lwt[128 * WROW];   // 34,816 B
    __shared__ int s_bad, s_nz;
    const int tid = threadIdx.x;
    const int b = blockIdx.x;

    // dtype probe (local per block; leading words are L2-hot)
    if (tid == 0) { s_bad = 0; s_nz = 0; }
    __syncthreads();
    {
        unsigned int wv = ((const unsigned int*)dpm)[tid];   // fp32 dp_mask words: 0 or 2.5f
        if (wv != 0u && wv != 0x40200000u) atomicAdd(&s_bad, 1);
        if (((const unsigned int*)ei)[2 * tid + 1] != 0u) atomicAdd(&s_nz, 1);
    }
    __syncthreads();
    const int f32 = (s_bad == 0) ? 1 : 0;
    const int i64 = (s_nz == 0) ? 1 : 0;
    if (b == 0 && tid == 0) { flags[0] = f32; flags[1] = i64; }

    if (b < GEMMB) {
        const int lane = tid & 63;
        const int wave = tid >> 6;
        const int lrow = lane & 15;
        const int quad = lane >> 4;
        const int row0w = b * 128 + wave * 32;

        // ---- load x rows once (bf16 fragments in registers for both halves) ----
        short8 a[2][4];
        #pragma unroll
        for (int t = 0; t < 2; t++)
            #pragma unroll
            for (int q = 0; q < 4; q++)
                #pragma unroll
                for (int j = 0; j < 8; j++) a[t][q][j] = 0;

        #pragma unroll
        for (int t = 0; t < 2; t++) {
            int row = row0w + t * 16 + lrow;
            if (row < NN) {
                if (f32) {
                    const float* xp = (const float*)x + (long long)row * FIN + quad * 8;
                    #pragma unroll
                    for (int q = 0; q < 4; q++) {
                        floatx4 u0 = *(const floatx4*)(xp + q * 32);
                        floatx4 u1 = *(const floatx4*)(xp + q * 32 + 4);
                        #pragma unroll
                        for (int j = 0; j < 4; j++) {
                            a[t][q][j]     = (short)f2bf(u0[j]);
                            a[t][q][j + 4] = (short)f2bf(u1[j]);
                        }
                    }
                } else {
                    const unsigned short* xp = (const unsigned short*)x + (long long)row * FIN + quad * 8;
                    #pragma unroll
                    for (int q = 0; q < 4; q++) a[t][q] = *(const short8*)(xp + q * 32);
                }
            }
        }

        #pragma unroll
        for (int ch = 0; ch < 2; ch++) {
            if (ch) __syncthreads();       // all reads of previous half done
            // ---- stage W^T half: two threads per column, 64 k's each; coalesced ----
            {
                const int lcol = tid & 127;
                const int col = ch * 128 + lcol;
                const int k0 = (tid >> 7) * 64;
                if (f32) {
                    const float* wp = (const float*)W + col;
                    for (int k = k0; k < k0 + 64; k++) lwt[lcol * WROW + k] = f2bf(wp[(long long)k * HC]);
                } else {
                    const unsigned short* wp = (const unsigned short*)W + col;
                    for (int k = k0; k < k0 + 64; k++) lwt[lcol * WROW + k] = wp[(long long)k * HC];
                }
            }
            __syncthreads();

            float sS[2][4], sD[2][4];
            #pragma unroll 4
            for (int ct = 0; ct < 8; ct++) {
                if ((ct & 1) == 0) {
                    #pragma unroll
                    for (int t = 0; t < 2; t++)
                        #pragma unroll
                        for (int r = 0; r < 4; r++) { sS[t][r] = 0.f; sD[t][r] = 0.f; }
                }
                floatx4 acc0 = {0.f, 0.f, 0.f, 0.f};
                floatx4 acc1 = {0.f, 0.f, 0.f, 0.f};
                const unsigned short* wp = lwt + (ct * 16 + lrow) * WROW + quad * 8;
                #pragma unroll
                for (int q = 0; q < 4; q++) {
                    short8 bb = *(const short8*)(wp + q * 32);
                    acc0 = __builtin_amdgcn_mfma_f32_16x16x32_bf16(a[0][q], bb, acc0, 0, 0, 0);
                    acc1 = __builtin_amdgcn_mfma_f32_16x16x32_bf16(a[1][q], bb, acc1, 0, 0, 0);
                }
                const int gcol = ch * 128 + ct * 16 + lrow;
                // C/D: col = lane&15, row = quad*4 + reg
                #pragma unroll
                for (int r = 0; r < 4; r++) {
                    int orow = row0w + quad * 4 + r;
                    if (orow < NN) h[(long long)orow * HC + gcol] = f2bf(acc0[r]);
                    int orow1 = orow + 16;
                    if (orow1 < NN) h[(long long)orow1 * HC + gcol] = f2bf(acc1[r]);
                }
                float tS = ldf(as_, f32, gcol);
                float tD = ldf(ad_, f32, gcol);
                #pragma unroll
                for (int r = 0; r < 4; r++) {
                    sS[0][r] += acc0[r] * tS;  sS[1][r] += acc1[r] * tS;
                    sD[0][r] += acc0[r] * tD;  sD[1][r] += acc1[r] * tD;
                }
                if (ct & 1) {   // head (ch*4 + ct>>1) complete: reduce over 16-lane col group
                    #pragma unroll
                    for (int m = 1; m <= 8; m <<= 1)
                        #pragma unroll
                        for (int t = 0; t < 2; t++)
                            #pragma unroll
                            for (int r = 0; r < 4; r++) {
                                sS[t][r] += __shfl_xor(sS[t][r], m);
                                sD[t][r] += __shfl_xor(sD[t][r], m);
                            }
                    int hd = ch * 4 + (ct >> 1);
                    if (lrow < 8) {
                        int t2 = lrow >> 2, rr = lrow & 3;
                        int row = row0w + t2 * 16 + quad * 4 + rr;
                        if (row < NN) a_src[row * NH + hd] = sel8(sS, t2, rr);
                    } else {
                        int lr = lrow - 8;
                        int t2 = lr >> 2, rr = lr & 3;
                        int row = row0w + t2 * 16 + quad * 4 + rr;
                        if (row < NN) a_dst[row * NH + hd] = sel8(sD, t2, rr);
                    }
                }
            }
        }
    } else {
        // ---- bucket fill: one edge per thread ----
        const long long e = (long long)(b - GEMMB) * 256 + tid;   // < NE by construction
        int dst = lde(ei, i64, e);
        int src = lde(ei, i64, (long long)NE + e);
        unsigned int msk = 0;
        if (f32) {
            const floatx4* dp = (const floatx4*)((const float*)dpm + e * 8);
            floatx4 d0 = dp[0], d1 = dp[1];
            #pragma unroll
            for (int j = 0; j < 4; j++) {
                msk |= (d0[j] != 0.f ? 1u : 0u) << j;
                msk |= (d1[j] != 0.f ? 1u : 0u) << (4 + j);
            }
        } else {
            short8 dd = *(const short8*)((const unsigned short*)dpm + e * 8);
            #pragma unroll
            for (int j = 0; j < 8; j++) msk |= (dd[j] != 0 ? 1u : 0u) << j;
        }
        unsigned int entry = (unsigned int)src | (msk << 16);
        int pos = atomicAdd(&cnt[dst], 1);
        if (pos < cap) bucket[((long long)dst << capl2) + pos] = entry;
        else {
            int op = atomicAdd(ovfcnt, 1);
            if (op < OVFCAP) ovf[op] = make_int2(dst, (int)entry);
        }
    }
}

// ---- K2 v4: TWO nodes per wave, chains interleaved at statement level so the
//      scheduler overlaps node B's loads with node A's latency (2x MLP at
//      unchanged occupancy). Core per-node structure is the proven v2:
//      producer/consumer split, dropout bit in the weight's sign, uniform
//      bucket loads, SGPR-base h-gathers, branch-free padded chunks.
__global__ __launch_bounds__(256) void k_aggr(
        const int* __restrict__ cnt, const int* __restrict__ ovfcnt,
        const unsigned int* __restrict__ bucket, const int2* __restrict__ ovf,
        const float* __restrict__ a_src, const float* __restrict__ a_dst,
        const unsigned short* __restrict__ h, const void* __restrict__ dps,
        const int* __restrict__ flags, const void* __restrict__ bs_,
        void* __restrict__ out, int cap, int capl2) {
    const int wid = blockIdx.x * 4 + (threadIdx.x >> 6);
    const int lane = threadIdx.x & 63;
    const int nA = wid * 2;
    if (nA >= NN) return;
    const int uA = __builtin_amdgcn_readfirstlane(nA);   // wave-uniform -> SGPR
    const int uB = uA + 1;                               // uA even, uB < NN (NN even)
    const int f32 = flags[0];
    int novf = *ovfcnt; novf = novf > OVFCAP ? OVFCAP : novf;
    int mnA = cnt[uA]; mnA = mnA < cap ? mnA : cap;
    int mnB = cnt[uB]; mnB = mnB < cap ? mnB : cap;
    const unsigned int* __restrict__ bpA = bucket + ((long long)uA << capl2);
    const unsigned int* __restrict__ bpB = bucket + ((long long)uB << capl2);

    const int hh = lane >> 3;              // head owned by this lane
    const int e8 = lane & 7;               // producer's edge slot within chunk
    const int badr = (lane & 56) << 2;     // bpermute byte base of this head group
    const int cb = lane * 4;               // channel base within h-row (shorts)
    const float adA = a_dst[uA * NH + hh];
    const float adB = a_dst[uB * NH + hh];

    float dnA = 0.f, dnB = 0.f;
    float aA0 = 0.f, aA1 = 0.f, aA2 = 0.f, aA3 = 0.f;
    float aB0 = 0.f, aB1 = 0.f, aB2 = 0.f, aB3 = 0.f;

    const int mx = mnA > mnB ? mnA : mnB;
    for (int j = 0; j < mx; j += 8) {
        // uniform chunk loads for BOTH nodes (scalar loads; issue early)
        unsigned int A0 = bpA[j + 0], A1 = bpA[j + 1], A2 = bpA[j + 2], A3 = bpA[j + 3],
                     A4 = bpA[j + 4], A5 = bpA[j + 5], A6 = bpA[j + 6], A7 = bpA[j + 7];
        unsigned int B0 = bpB[j + 0], B1 = bpB[j + 1], B2 = bpB[j + 2], B3 = bpB[j + 3],
                     B4 = bpB[j + 4], B5 = bpB[j + 5], B6 = bpB[j + 6], B7 = bpB[j + 7];

        // ---- producers: one (edge,head) per lane, both nodes; clamps keep
        //      loads in-bounds, out-of-range lanes contribute w = 0.
        const int idx = j + e8;
        int icA = idx < mnA ? idx : (mnA > 0 ? mnA - 1 : 0);
        int icB = idx < mnB ? idx : (mnB > 0 ? mnB - 1 : 0);
        unsigned int ueA = bpA[icA];
        unsigned int ueB = bpB[icB];
        float alA = a_src[(int)(ueA & 0xFFFFu) * NH + hh] + adA;
        float alB = a_src[(int)(ueB & 0xFFFFu) * NH + hh] + adB;
        float wA = __expf(fmaxf(alA, 0.2f * alA)); wA = idx < mnA ? wA : 0.f;
        float wB = __expf(fmaxf(alB, 0.2f * alB)); wB = idx < mnB ? wB : 0.f;
        dnA += wA; dnB += wB;
        float wsA = ((ueA >> (16 + hh)) & 1u) ? wA : -wA;   // sign carries dropout bit
        float wsB = ((ueB >> (16 + hh)) & 1u) ? wB : -wB;

        // ---- consumer weight broadcasts (1 ds_bpermute per edge, both nodes)
        #define GATW(N, K) float w##N##K = bperm(badr + 4 * K, ws##N);
        GATW(A,0) GATW(A,1) GATW(A,2) GATW(A,3) GATW(A,4) GATW(A,5) GATW(A,6) GATW(A,7)
        GATW(B,0) GATW(B,1) GATW(B,2) GATW(B,3) GATW(B,4) GATW(B,5) GATW(B,6) GATW(B,7)
        #undef GATW

        // ---- h-row gathers: SGPR base per edge + constant lane offset
        #define GATH(N, K) \
            const unsigned short* hp##N##K = h + \
                (((long long)(__builtin_amdgcn_readfirstlane((int)N##K) & 0xFFFF)) << 8); \
            uint2 v##N##K = make_uint2(0u, 0u); \
            if (w##N##K > 0.f) v##N##K = *(const uint2*)(hp##N##K + cb);
        GATH(A,0) GATH(A,1) GATH(A,2) GATH(A,3) GATH(A,4) GATH(A,5) GATH(A,6) GATH(A,7)
        GATH(B,0) GATH(B,1) GATH(B,2) GATH(B,3) GATH(B,4) GATH(B,5) GATH(B,6) GATH(B,7)
        #undef GATH

        // ---- unconditional MACs: dropped/padded edges have v == 0
        #define MACC(N, K) { float p = w##N##K * 2.5f; \
            a##N##0 = fmaf(p, blo(v##N##K.x), a##N##0); a##N##1 = fmaf(p, bhi(v##N##K.x), a##N##1); \
            a##N##2 = fmaf(p, blo(v##N##K.y), a##N##2); a##N##3 = fmaf(p, bhi(v##N##K.y), a##N##3); }
        MACC(A,0) MACC(A,1) MACC(A,2) MACC(A,3) MACC(A,4) MACC(A,5) MACC(A,6) MACC(A,7)
        MACC(B,0) MACC(B,1) MACC(B,2) MACC(B,3) MACC(B,4) MACC(B,5) MACC(B,6) MACC(B,7)
        #undef MACC
    }

    // reduce producer denominators across the 8 lanes of each head group
    dnA += __shfl_xor(dnA, 1); dnA += __shfl_xor(dnA, 2); dnA += __shfl_xor(dnA, 4);
    dnB += __shfl_xor(dnB, 1); dnB += __shfl_xor(dnB, 2); dnB += __shfl_xor(dnB, 4);

    // overflow sweep (novf ~ 0 in practice; correct for any value)
    for (int i = 0; i < novf; i++) {
        int2 tv = ovf[i];
        if (tv.x == nA || tv.x == uB) {
            unsigned int u = (unsigned int)tv.y;
            int src = (int)(u & 0xFFFFu);
            float ad = (tv.x == nA) ? adA : adB;
            float w = __expf(lrelu(a_src[src * NH + hh] + ad));
            uint2 hv = make_uint2(0u, 0u);
            if ((u >> (16 + hh)) & 1u) hv = *(const uint2*)(h + ((long long)src << 8) + cb);
            float p = w * 2.5f;
            if (tv.x == nA) {
                dnA += w;
                aA0 = fmaf(p, blo(hv.x), aA0); aA1 = fmaf(p, bhi(hv.x), aA1);
                aA2 = fmaf(p, blo(hv.y), aA2); aA3 = fmaf(p, bhi(hv.y), aA3);
            } else {
                dnB += w;
                aB0 = fmaf(p, blo(hv.x), aB0); aB1 = fmaf(p, bhi(hv.x), aB1);
                aB2 = fmaf(p, blo(hv.y), aB2); aB3 = fmaf(p, bhi(hv.y), aB3);
            }
        }
    }
    { // self-loops, both nodes
        float wSA = __expf(lrelu(a_src[uA * NH + hh] + adA));
        float wSB = __expf(lrelu(a_src[uB * NH + hh] + adB));
        dnA += wSA; dnB += wSB;
        float pSA = wSA * ldf(dps, f32, (long long)uA * NH + hh);
        float pSB = wSB * ldf(dps, f32, (long long)uB * NH + hh);
        uint2 hvA = *(const uint2*)(h + ((long long)uA << 8) + cb);
        uint2 hvB = *(const uint2*)(h + ((long long)uB << 8) + cb);
        aA0 = fmaf(pSA, blo(hvA.x), aA0); aA1 = fmaf(pSA, bhi(hvA.x), aA1);
        aA2 = fmaf(pSA, blo(hvA.y), aA2); aA3 = fmaf(pSA, bhi(hvA.y), aA3);
        aB0 = fmaf(pSB, blo(hvB.x), aB0); aB1 = fmaf(pSB, bhi(hvB.x), aB1);
        aB2 = fmaf(pSB, blo(hvB.y), aB2); aB3 = fmaf(pSB, bhi(hvB.y), aB3);
    }
    float invA = 1.0f / dnA, invB = 1.0f / dnB;
    float b0 = ldf(bs_, f32, cb + 0), b1 = ldf(bs_, f32, cb + 1);
    float b2 = ldf(bs_, f32, cb + 2), b3 = ldf(bs_, f32, cb + 3);
    if (f32) {
        floatx4 oA = {aA0 * invA + b0, aA1 * invA + b1, aA2 * invA + b2, aA3 * invA + b3};
        floatx4 oB = {aB0 * invB + b0, aB1 * invB + b1, aB2 * invB + b2, aB3 * invB + b3};
        *(floatx4*)((float*)out + (long long)uA * HC + cb) = oA;
        *(floatx4*)((float*)out + (long long)uB * HC + cb) = oB;
    } else {
        short4v oA, oB;
        oA[0] = (short)f2bf(aA0 * invA + b0); oA[1] = (short)f2bf(aA1 * invA + b1);
        oA[2] = (short)f2bf(aA2 * invA + b2); oA[3] = (short)f2bf(aA3 * invA + b3);
        oB[0] = (short)f2bf(aB0 * invB + b0); oB[1] = (short)f2bf(aB1 * invB + b1);
        oB[2] = (short)f2bf(aB2 * invB + b2); oB[3] = (short)f2bf(aB3 * invB + b3);
        *(short4v*)((unsigned short*)out + (long long)uA * HC + cb) = oA;
        *(short4v*)((unsigned short*)out + (long long)uB * HC + cb) = oB;
    }
}

extern "C" void kernel_launch(void* const* d_in, const int* in_sizes, int n_in,
                              void* d_out, int out_size, void* d_ws, size_t ws_size,
                              hipStream_t stream) {
    const void* x       = d_in[0];
    const int*  ei      = (const int*)d_in[1];
    const void* dp_mask = d_in[2];
    const void* dp_self = d_in[3];
    const void* W       = d_in[4];
    const void* att_s   = d_in[5];
    const void* att_d   = d_in[6];
    const void* bias    = d_in[7];

    char* w = (char*)d_ws;
    unsigned short* h      = (unsigned short*)(w + 0);             // 25,600,000
    float*          a_src  = (float*)(w + 25600000);               //  1,600,000
    float*          a_dst  = (float*)(w + 27200000);               //  1,600,000
    int*            cnt    = (int*)(w + 28800000);                 //    200,000
    int*            ovfcnt = (int*)(w + 29000000);                 //          4
    int*            flags  = (int*)(w + 29000064);                 //          8
    int2*           ovf    = (int2*)(w + 29000960);                //  1,048,576
    unsigned int*   bucket = (unsigned int*)(w + 30049536);        //  cap*200,000

    // 512 B slack: k_aggr chunk reads may run up to 7 entries past the last
    // node's bucket row (values masked, never used as addresses).
    long long avail = (long long)ws_size - 30049536LL - 512LL;
    int cap = 64, capl2 = 6;
    while (cap > 4 && (long long)cap * 200000LL > avail) { cap >>= 1; capl2--; }

    // zero cnt + ovfcnt (+flags; flags rewritten by k_front before k_aggr reads)
    hipMemsetAsync(cnt, 0, 200960, stream);
    k_front<<<NBLK1, 256, 0, stream>>>(x, ei, dp_mask, W, att_s, att_d,
                                       flags, h, a_src, a_dst, cnt, ovfcnt, bucket, ovf,
                                       cap, capl2);
    k_aggr<<<NN / 8, 256, 0, stream>>>(cnt, ovfcnt, bucket, ovf, a_src, a_dst, h,
                                       dp_self, flags, bias, d_out, cap, capl2);
}

// Round 6
// 203.881 us; speedup vs baseline: 1.1603x; 1.0273x over previous
//
#include <hip/hip_runtime.h>

#define NN 50000
#define FIN 128
#define HC 256
#define NH 8
#define NE 800000
#define WROW 136        // padded LDS row (shorts); rows 16B-aligned
#define GEMMB 391       // 391*128 rows >= NN; each gemm block does BOTH column halves
#define NBLK1 3516      // 391 gemm + 3125 fill (3125*256 == NE exactly)
#define OVFCAP 131072

typedef __attribute__((ext_vector_type(8))) short short8;
typedef __attribute__((ext_vector_type(4))) short short4v;
typedef __attribute__((ext_vector_type(4))) float floatx4;

__device__ __forceinline__ float bf2f(unsigned short u) {
    union { unsigned int i; float f; } v; v.i = ((unsigned int)u) << 16; return v.f;
}
__device__ __forceinline__ unsigned short f2bf(float f) {
    union { float f; unsigned int i; } v; v.f = f;
    unsigned int r = v.i + 0x7fffu + ((v.i >> 16) & 1u);
    return (unsigned short)(r >> 16);
}
__device__ __forceinline__ float lrelu(float x) { return x > 0.f ? x : 0.2f * x; }
__device__ __forceinline__ float ldf(const void* p, int f32, long long i) {
    return f32 ? ((const float*)p)[i] : bf2f(((const unsigned short*)p)[i]);
}
__device__ __forceinline__ int lde(const int* ei, int i64, long long i) {
    return i64 ? (int)((const long long*)ei)[i] : ei[i];
}
__device__ __forceinline__ float sel8(const float s[2][4], int t2, int rr) {
    float a0 = t2 ? s[1][0] : s[0][0];
    float a1 = t2 ? s[1][1] : s[0][1];
    float a2 = t2 ? s[1][2] : s[0][2];
    float a3 = t2 ? s[1][3] : s[0][3];
    return (rr == 0) ? a0 : ((rr == 1) ? a1 : ((rr == 2) ? a2 : a3));
}
// bf16 pair unpack from one dword: low short = <<16, high short = mask (no shift)
__device__ __forceinline__ float blo(unsigned int u) {
    union { unsigned int i; float f; } v; v.i = u << 16; return v.f;
}
__device__ __forceinline__ float bhi(unsigned int u) {
    union { unsigned int i; float f; } v; v.i = u & 0xFFFF0000u; return v.f;
}

// ---- K1 (unchanged from R5 best): blocks < GEMMB: MFMA GEMM + attention
//      scores — x loaded ONCE into registers, W staged per 128-col half into a
//      34,816 B LDS buffer (4 blocks/CU), two sequential halves.
//      blocks >= GEMMB: bucket fill, 1 edge/thread.
__global__ __launch_bounds__(256) void k_front(
        const void* __restrict__ x, const int* __restrict__ ei,
        const void* __restrict__ dpm, const void* __restrict__ W,
        const void* __restrict__ as_, const void* __restrict__ ad_,
        int* __restrict__ flags, unsigned short* __restrict__ h,
        float* __restrict__ a_src, float* __restrict__ a_dst,
        int* __restrict__ cnt, int* __restrict__ ovfcnt,
        unsigned int* __restrict__ bucket, int2* __restrict__ ovf,
        int cap, int capl2) {
    __shared__ unsigned short lwt[128 * WROW];   // 34,816 B
    __shared__ int s_bad, s_nz;
    const int tid = threadIdx.x;
    const int b = blockIdx.x;

    // dtype probe (local per block; leading words are L2-hot)
    if (tid == 0) { s_bad = 0; s_nz = 0; }
    __syncthreads();
    {
        unsigned int wv = ((const unsigned int*)dpm)[tid];   // fp32 dp_mask words: 0 or 2.5f
        if (wv != 0u && wv != 0x40200000u) atomicAdd(&s_bad, 1);
        if (((const unsigned int*)ei)[2 * tid + 1] != 0u) atomicAdd(&s_nz, 1);
    }
    __syncthreads();
    const int f32 = (s_bad == 0) ? 1 : 0;
    const int i64 = (s_nz == 0) ? 1 : 0;
    if (b == 0 && tid == 0) { flags[0] = f32; flags[1] = i64; }

    if (b < GEMMB) {
        const int lane = tid & 63;
        const int wave = tid >> 6;
        const int lrow = lane & 15;
        const int quad = lane >> 4;
        const int row0w = b * 128 + wave * 32;

        // ---- load x rows once (bf16 fragments in registers for both halves) ----
        short8 a[2][4];
        #pragma unroll
        for (int t = 0; t < 2; t++)
            #pragma unroll
            for (int q = 0; q < 4; q++)
                #pragma unroll
                for (int j = 0; j < 8; j++) a[t][q][j] = 0;

        #pragma unroll
        for (int t = 0; t < 2; t++) {
            int row = row0w + t * 16 + lrow;
            if (row < NN) {
                if (f32) {
                    const float* xp = (const float*)x + (long long)row * FIN + quad * 8;
                    #pragma unroll
                    for (int q = 0; q < 4; q++) {
                        floatx4 u0 = *(const floatx4*)(xp + q * 32);
                        floatx4 u1 = *(const floatx4*)(xp + q * 32 + 4);
                        #pragma unroll
                        for (int j = 0; j < 4; j++) {
                            a[t][q][j]     = (short)f2bf(u0[j]);
                            a[t][q][j + 4] = (short)f2bf(u1[j]);
                        }
                    }
                } else {
                    const unsigned short* xp = (const unsigned short*)x + (long long)row * FIN + quad * 8;
                    #pragma unroll
                    for (int q = 0; q < 4; q++) a[t][q] = *(const short8*)(xp + q * 32);
                }
            }
        }

        #pragma unroll
        for (int ch = 0; ch < 2; ch++) {
            if (ch) __syncthreads();       // all reads of previous half done
            // ---- stage W^T half: two threads per column, 64 k's each; coalesced ----
            {
                const int lcol = tid & 127;
                const int col = ch * 128 + lcol;
                const int k0 = (tid >> 7) * 64;
                if (f32) {
                    const float* wp = (const float*)W + col;
                    for (int k = k0; k < k0 + 64; k++) lwt[lcol * WROW + k] = f2bf(wp[(long long)k * HC]);
                } else {
                    const unsigned short* wp = (const unsigned short*)W + col;
                    for (int k = k0; k < k0 + 64; k++) lwt[lcol * WROW + k] = wp[(long long)k * HC];
                }
            }
            __syncthreads();

            float sS[2][4], sD[2][4];
            #pragma unroll 4
            for (int ct = 0; ct < 8; ct++) {
                if ((ct & 1) == 0) {
                    #pragma unroll
                    for (int t = 0; t < 2; t++)
                        #pragma unroll
                        for (int r = 0; r < 4; r++) { sS[t][r] = 0.f; sD[t][r] = 0.f; }
                }
                floatx4 acc0 = {0.f, 0.f, 0.f, 0.f};
                floatx4 acc1 = {0.f, 0.f, 0.f, 0.f};
                const unsigned short* wp = lwt + (ct * 16 + lrow) * WROW + quad * 8;
                #pragma unroll
                for (int q = 0; q < 4; q++) {
                    short8 bb = *(const short8*)(wp + q * 32);
                    acc0 = __builtin_amdgcn_mfma_f32_16x16x32_bf16(a[0][q], bb, acc0, 0, 0, 0);
                    acc1 = __builtin_amdgcn_mfma_f32_16x16x32_bf16(a[1][q], bb, acc1, 0, 0, 0);
                }
                const int gcol = ch * 128 + ct * 16 + lrow;
                // C/D: col = lane&15, row = quad*4 + reg
                #pragma unroll
                for (int r = 0; r < 4; r++) {
                    int orow = row0w + quad * 4 + r;
                    if (orow < NN) h[(long long)orow * HC + gcol] = f2bf(acc0[r]);
                    int orow1 = orow + 16;
                    if (orow1 < NN) h[(long long)orow1 * HC + gcol] = f2bf(acc1[r]);
                }
                float tS = ldf(as_, f32, gcol);
                float tD = ldf(ad_, f32, gcol);
                #pragma unroll
                for (int r = 0; r < 4; r++) {
                    sS[0][r] += acc0[r] * tS;  sS[1][r] += acc1[r] * tS;
                    sD[0][r] += acc0[r] * tD;  sD[1][r] += acc1[r] * tD;
                }
                if (ct & 1) {   // head (ch*4 + ct>>1) complete: reduce over 16-lane col group
                    #pragma unroll
                    for (int m = 1; m <= 8; m <<= 1)
                        #pragma unroll
                        for (int t = 0; t < 2; t++)
                            #pragma unroll
                            for (int r = 0; r < 4; r++) {
                                sS[t][r] += __shfl_xor(sS[t][r], m);
                                sD[t][r] += __shfl_xor(sD[t][r], m);
                            }
                    int hd = ch * 4 + (ct >> 1);
                    if (lrow < 8) {
                        int t2 = lrow >> 2, rr = lrow & 3;
                        int row = row0w + t2 * 16 + quad * 4 + rr;
                        if (row < NN) a_src[row * NH + hd] = sel8(sS, t2, rr);
                    } else {
                        int lr = lrow - 8;
                        int t2 = lr >> 2, rr = lr & 3;
                        int row = row0w + t2 * 16 + quad * 4 + rr;
                        if (row < NN) a_dst[row * NH + hd] = sel8(sD, t2, rr);
                    }
                }
            }
        }
    } else {
        // ---- bucket fill: one edge per thread ----
        const long long e = (long long)(b - GEMMB) * 256 + tid;   // < NE by construction
        int dst = lde(ei, i64, e);
        int src = lde(ei, i64, (long long)NE + e);
        unsigned int msk = 0;
        if (f32) {
            const floatx4* dp = (const floatx4*)((const float*)dpm + e * 8);
            floatx4 d0 = dp[0], d1 = dp[1];
            #pragma unroll
            for (int j = 0; j < 4; j++) {
                msk |= (d0[j] != 0.f ? 1u : 0u) << j;
                msk |= (d1[j] != 0.f ? 1u : 0u) << (4 + j);
            }
        } else {
            short8 dd = *(const short8*)((const unsigned short*)dpm + e * 8);
            #pragma unroll
            for (int j = 0; j < 8; j++) msk |= (dd[j] != 0 ? 1u : 0u) << j;
        }
        unsigned int entry = (unsigned int)src | (msk << 16);
        int pos = atomicAdd(&cnt[dst], 1);
        if (pos < cap) bucket[((long long)dst << capl2) + pos] = entry;
        else {
            int op = atomicAdd(ovfcnt, 1);
            if (op < OVFCAP) ovf[op] = make_int2(dst, (int)entry);
        }
    }
}

// ---- K2 v5: lane L owns edge L (cap == 64 == wave size).
//      Upfront phase (full MLP, no serial chain): one coalesced bucket load,
//      TWO contiguous floatx4 a_src loads per lane (all 8 head scores of its
//      edge), 8 exps; signed weights (sign = dropout bit) stored to a per-wave
//      LDS table [head][edge] (padded, conflict-free). Chunk loop is then just:
//      broadcast ds_read of weights + scalar readlane for the h-row base +
//      gated h-gather + MACs — chunks are data-independent and pipeline.
__global__ __launch_bounds__(256) void k_aggr(
        const int* __restrict__ cnt, const int* __restrict__ ovfcnt,
        const unsigned int* __restrict__ bucket, const int2* __restrict__ ovf,
        const float* __restrict__ a_src, const float* __restrict__ a_dst,
        const unsigned short* __restrict__ h, const void* __restrict__ dps,
        const int* __restrict__ flags, const void* __restrict__ bs_,
        void* __restrict__ out, int cap, int capl2) {
    __shared__ float wsh[4 * 8 * 72];      // 4 waves x [8 heads][72 (64+pad)] = 9,216 B
    const int node = blockIdx.x * 4 + (threadIdx.x >> 6);
    const int lane = threadIdx.x & 63;
    if (node >= NN) return;
    const int unode = __builtin_amdgcn_readfirstlane(node);   // wave-uniform -> SGPR
    const int wave = threadIdx.x >> 6;
    const int f32 = flags[0];
    int novf = *ovfcnt; novf = novf > OVFCAP ? OVFCAP : novf;
    int mn = cnt[unode]; mn = mn < cap ? mn : cap;
    const unsigned int* __restrict__ bp = bucket + ((long long)unode << capl2);

    const int hh = lane >> 3;              // head owned by this lane (consumer)
    const int cb = lane * 4;               // channel base within h-row (shorts)
    float* __restrict__ wl = wsh + wave * (8 * 72);

    // ---- upfront: edge L -> lane L; all-head scores with contiguous loads ----
    int lc = lane < mn ? lane : (mn > 0 ? mn - 1 : 0);
    unsigned int ue = bp[lc];                                   // coalesced
    int esrc = (int)(ue & 0xFFFFu);
    floatx4 as0 = *(const floatx4*)(a_src + esrc * NH);         // 8 head scores,
    floatx4 as1 = *(const floatx4*)(a_src + esrc * NH + 4);     // 32 B contiguous
    // a_dst for all heads: wave-uniform (scalar loads)
    const float* adp = a_dst + unode * NH;
    float ad[8];
    #pragma unroll
    for (int k = 0; k < 8; k++) ad[k] = adp[k];

    const bool valid = lane < mn;
    #pragma unroll
    for (int k = 0; k < 8; k++) {
        float al = (k < 4 ? as0[k & 3] : as1[k & 3]) + ad[k];
        float w = __expf(fmaxf(al, 0.2f * al));
        w = valid ? w : 0.f;
        float ws = ((ue >> (16 + k)) & 1u) ? w : -w;            // sign = dropout bit
        wl[k * 72 + lane] = ws;                                 // [head][edge], pad 72
    }
    __asm__ volatile("s_waitcnt lgkmcnt(0)" ::: "memory");      // wave-local LDS ready

    float dn = 0.f;
    float acc0 = 0.f, acc1 = 0.f, acc2 = 0.f, acc3 = 0.f;
    const float* __restrict__ wr = wl + hh * 72;                // consumer weight row

    #pragma unroll
    for (int c = 0; c < 8; c++) {
        if (8 * c < mn) {                  // mn wave-uniform -> scalar branch
            #define CONS(K) { \
                float wv = wr[8 * c + K];                        /* broadcast read */ \
                dn += fabsf(wv); \
                int s##K = __builtin_amdgcn_readlane((int)ue, 8 * c + K) & 0xFFFF; \
                uint2 v = make_uint2(0u, 0u); \
                if (wv > 0.f) v = *(const uint2*)(h + ((long long)s##K << 8) + cb); \
                float p = wv * 2.5f; \
                acc0 = fmaf(p, blo(v.x), acc0); acc1 = fmaf(p, bhi(v.x), acc1); \
                acc2 = fmaf(p, blo(v.y), acc2); acc3 = fmaf(p, bhi(v.y), acc3); }
            CONS(0) CONS(1) CONS(2) CONS(3) CONS(4) CONS(5) CONS(6) CONS(7)
            #undef CONS
        }
    }

    // overflow sweep (novf ~ 0 in practice; correct for any value)
    for (int i = 0; i < novf; i++) {
        int2 tv = ovf[i];
        if (tv.x == node) {
            unsigned int u = (unsigned int)tv.y;
            int src = (int)(u & 0xFFFFu);
            float adh = a_dst[unode * NH + hh];
            float w = __expf(lrelu(a_src[src * NH + hh] + adh));
            dn += w;
            if ((u >> (16 + hh)) & 1u) {
                uint2 hv = *(const uint2*)(h + ((long long)src << 8) + cb);
                float p = w * 2.5f;
                acc0 = fmaf(p, blo(hv.x), acc0); acc1 = fmaf(p, bhi(hv.x), acc1);
                acc2 = fmaf(p, blo(hv.y), acc2); acc3 = fmaf(p, bhi(hv.y), acc3);
            }
        }
    }
    { // self-loop
        float adh = a_dst[unode * NH + hh];
        float wS = __expf(lrelu(a_src[unode * NH + hh] + adh));
        dn += wS;
        float pS = wS * ldf(dps, f32, (long long)unode * NH + hh);
        uint2 hv = *(const uint2*)(h + ((long long)unode << 8) + cb);
        acc0 = fmaf(pS, blo(hv.x), acc0); acc1 = fmaf(pS, bhi(hv.x), acc1);
        acc2 = fmaf(pS, blo(hv.y), acc2); acc3 = fmaf(pS, bhi(hv.y), acc3);
    }
    float inv = 1.0f / dn;
    float b0 = ldf(bs_, f32, cb + 0), b1 = ldf(bs_, f32, cb + 1);
    float b2 = ldf(bs_, f32, cb + 2), b3 = ldf(bs_, f32, cb + 3);
    if (f32) {
        floatx4 o = {acc0 * inv + b0, acc1 * inv + b1, acc2 * inv + b2, acc3 * inv + b3};
        *(floatx4*)((float*)out + (long long)node * HC + cb) = o;
    } else {
        short4v o;
        o[0] = (short)f2bf(acc0 * inv + b0);
        o[1] = (short)f2bf(acc1 * inv + b1);
        o[2] = (short)f2bf(acc2 * inv + b2);
        o[3] = (short)f2bf(acc3 * inv + b3);
        *(short4v*)((unsigned short*)out + (long long)node * HC + cb) = o;
    }
}

extern "C" void kernel_launch(void* const* d_in, const int* in_sizes, int n_in,
                              void* d_out, int out_size, void* d_ws, size_t ws_size,
                              hipStream_t stream) {
    const void* x       = d_in[0];
    const int*  ei      = (const int*)d_in[1];
    const void* dp_mask = d_in[2];
    const void* dp_self = d_in[3];
    const void* W       = d_in[4];
    const void* att_s   = d_in[5];
    const void* att_d   = d_in[6];
    const void* bias    = d_in[7];

    char* w = (char*)d_ws;
    unsigned short* h      = (unsigned short*)(w + 0);             // 25,600,000
    float*          a_src  = (float*)(w + 25600000);               //  1,600,000
    float*          a_dst  = (float*)(w + 27200000);               //  1,600,000
    int*            cnt    = (int*)(w + 28800000);                 //    200,000
    int*            ovfcnt = (int*)(w + 29000000);                 //          4
    int*            flags  = (int*)(w + 29000064);                 //          8
    int2*           ovf    = (int2*)(w + 29000960);                //  1,048,576
    unsigned int*   bucket = (unsigned int*)(w + 30049536);        //  cap*200,000

    // 512 B slack: k_aggr per-lane bucket reads stay within each node's row
    // (clamped), but keep margin anyway.
    long long avail = (long long)ws_size - 30049536LL - 512LL;
    int cap = 64, capl2 = 6;
    while (cap > 4 && (long long)cap * 200000LL > avail) { cap >>= 1; capl2--; }

    // zero cnt + ovfcnt (+flags; flags rewritten by k_front before k_aggr reads)
    hipMemsetAsync(cnt, 0, 200960, stream);
    k_front<<<NBLK1, 256, 0, stream>>>(x, ei, dp_mask, W, att_s, att_d,
                                       flags, h, a_src, a_dst, cnt, ovfcnt, bucket, ovf,
                                       cap, capl2);
    k_aggr<<<NN / 4, 256, 0, stream>>>(cnt, ovfcnt, bucket, ovf, a_src, a_dst, h,
                                       dp_self, flags, bias, d_out, cap, capl2);
}

// Round 7
// 201.316 us; speedup vs baseline: 1.1751x; 1.0127x over previous
//
#include <hip/hip_runtime.h>

#define NN 50000
#define FIN 128
#define HC 256
#define NH 8
#define NE 800000
#define WROW 136        // padded LDS row (shorts); rows 16B-aligned
#define GEMMB 391       // 391*128 rows >= NN; each gemm block does BOTH column halves
#define NBLK1 3516      // 391 gemm + 3125 fill (3125*256 == NE exactly)
#define OVFCAP 131072

typedef __attribute__((ext_vector_type(8))) short short8;
typedef __attribute__((ext_vector_type(4))) short short4v;
typedef __attribute__((ext_vector_type(4))) float floatx4;

__device__ __forceinline__ float bf2f(unsigned short u) {
    union { unsigned int i; float f; } v; v.i = ((unsigned int)u) << 16; return v.f;
}
__device__ __forceinline__ unsigned short f2bf(float f) {
    union { float f; unsigned int i; } v; v.f = f;
    unsigned int r = v.i + 0x7fffu + ((v.i >> 16) & 1u);
    return (unsigned short)(r >> 16);
}
__device__ __forceinline__ float lrelu(float x) { return x > 0.f ? x : 0.2f * x; }
__device__ __forceinline__ float ldf(const void* p, int f32, long long i) {
    return f32 ? ((const float*)p)[i] : bf2f(((const unsigned short*)p)[i]);
}
__device__ __forceinline__ float sel8(const float s[2][4], int t2, int rr) {
    float a0 = t2 ? s[1][0] : s[0][0];
    float a1 = t2 ? s[1][1] : s[0][1];
    float a2 = t2 ? s[1][2] : s[0][2];
    float a3 = t2 ? s[1][3] : s[0][3];
    return (rr == 0) ? a0 : ((rr == 1) ? a1 : ((rr == 2) ? a2 : a3));
}
// bf16 pair unpack from one dword: low short = <<16, high short = mask (no shift)
__device__ __forceinline__ float blo(unsigned int u) {
    union { unsigned int i; float f; } v; v.i = u << 16; return v.f;
}
__device__ __forceinline__ float bhi(unsigned int u) {
    union { unsigned int i; float f; } v; v.i = u & 0xFFFF0000u; return v.f;
}

// ---- K1: blocks < GEMMB: MFMA GEMM + attention scores (unchanged from R6).
//      blocks >= GEMMB: bucket fill, 1 edge/thread, NON-TEMPORAL streaming:
//      NT loads for ei/dpm (read-once), NT store for the bucket entry (no
//      write-allocate -> no cross-XCD L2 line ping-pong on the 12.8 MB
//      scattered 4B-store region; R6 counters showed 105 MB WRITE_SIZE vs
//      ~32 MB payload).
__global__ __launch_bounds__(256) void k_front(
        const void* __restrict__ x, const int* __restrict__ ei,
        const void* __restrict__ dpm, const void* __restrict__ W,
        const void* __restrict__ as_, const void* __restrict__ ad_,
        int* __restrict__ flags, unsigned short* __restrict__ h,
        float* __restrict__ a_src, float* __restrict__ a_dst,
        int* __restrict__ cnt, int* __restrict__ ovfcnt,
        unsigned int* __restrict__ bucket, int2* __restrict__ ovf,
        int cap, int capl2) {
    __shared__ unsigned short lwt[128 * WROW];   // 34,816 B
    __shared__ int s_bad, s_nz;
    const int tid = threadIdx.x;
    const int b = blockIdx.x;

    // dtype probe (local per block; leading words are L2-hot)
    if (tid == 0) { s_bad = 0; s_nz = 0; }
    __syncthreads();
    {
        unsigned int wv = ((const unsigned int*)dpm)[tid];   // fp32 dp_mask words: 0 or 2.5f
        if (wv != 0u && wv != 0x40200000u) atomicAdd(&s_bad, 1);
        if (((const unsigned int*)ei)[2 * tid + 1] != 0u) atomicAdd(&s_nz, 1);
    }
    __syncthreads();
    const int f32 = (s_bad == 0) ? 1 : 0;
    const int i64 = (s_nz == 0) ? 1 : 0;
    if (b == 0 && tid == 0) { flags[0] = f32; flags[1] = i64; }

    if (b < GEMMB) {
        const int lane = tid & 63;
        const int wave = tid >> 6;
        const int lrow = lane & 15;
        const int quad = lane >> 4;
        const int row0w = b * 128 + wave * 32;

        // ---- load x rows once (bf16 fragments in registers for both halves) ----
        short8 a[2][4];
        #pragma unroll
        for (int t = 0; t < 2; t++)
            #pragma unroll
            for (int q = 0; q < 4; q++)
                #pragma unroll
                for (int j = 0; j < 8; j++) a[t][q][j] = 0;

        #pragma unroll
        for (int t = 0; t < 2; t++) {
            int row = row0w + t * 16 + lrow;
            if (row < NN) {
                if (f32) {
                    const float* xp = (const float*)x + (long long)row * FIN + quad * 8;
                    #pragma unroll
                    for (int q = 0; q < 4; q++) {
                        floatx4 u0 = *(const floatx4*)(xp + q * 32);
                        floatx4 u1 = *(const floatx4*)(xp + q * 32 + 4);
                        #pragma unroll
                        for (int j = 0; j < 4; j++) {
                            a[t][q][j]     = (short)f2bf(u0[j]);
                            a[t][q][j + 4] = (short)f2bf(u1[j]);
                        }
                    }
                } else {
                    const unsigned short* xp = (const unsigned short*)x + (long long)row * FIN + quad * 8;
                    #pragma unroll
                    for (int q = 0; q < 4; q++) a[t][q] = *(const short8*)(xp + q * 32);
                }
            }
        }

        #pragma unroll
        for (int ch = 0; ch < 2; ch++) {
            if (ch) __syncthreads();       // all reads of previous half done
            // ---- stage W^T half: two threads per column, 64 k's each; coalesced ----
            {
                const int lcol = tid & 127;
                const int col = ch * 128 + lcol;
                const int k0 = (tid >> 7) * 64;
                if (f32) {
                    const float* wp = (const float*)W + col;
                    for (int k = k0; k < k0 + 64; k++) lwt[lcol * WROW + k] = f2bf(wp[(long long)k * HC]);
                } else {
                    const unsigned short* wp = (const unsigned short*)W + col;
                    for (int k = k0; k < k0 + 64; k++) lwt[lcol * WROW + k] = wp[(long long)k * HC];
                }
            }
            __syncthreads();

            float sS[2][4], sD[2][4];
            #pragma unroll 4
            for (int ct = 0; ct < 8; ct++) {
                if ((ct & 1) == 0) {
                    #pragma unroll
                    for (int t = 0; t < 2; t++)
                        #pragma unroll
                        for (int r = 0; r < 4; r++) { sS[t][r] = 0.f; sD[t][r] = 0.f; }
                }
                floatx4 acc0 = {0.f, 0.f, 0.f, 0.f};
                floatx4 acc1 = {0.f, 0.f, 0.f, 0.f};
                const unsigned short* wp = lwt + (ct * 16 + lrow) * WROW + quad * 8;
                #pragma unroll
                for (int q = 0; q < 4; q++) {
                    short8 bb = *(const short8*)(wp + q * 32);
                    acc0 = __builtin_amdgcn_mfma_f32_16x16x32_bf16(a[0][q], bb, acc0, 0, 0, 0);
                    acc1 = __builtin_amdgcn_mfma_f32_16x16x32_bf16(a[1][q], bb, acc1, 0, 0, 0);
                }
                const int gcol = ch * 128 + ct * 16 + lrow;
                // C/D: col = lane&15, row = quad*4 + reg
                #pragma unroll
                for (int r = 0; r < 4; r++) {
                    int orow = row0w + quad * 4 + r;
                    if (orow < NN) h[(long long)orow * HC + gcol] = f2bf(acc0[r]);
                    int orow1 = orow + 16;
                    if (orow1 < NN) h[(long long)orow1 * HC + gcol] = f2bf(acc1[r]);
                }
                float tS = ldf(as_, f32, gcol);
                float tD = ldf(ad_, f32, gcol);
                #pragma unroll
                for (int r = 0; r < 4; r++) {
                    sS[0][r] += acc0[r] * tS;  sS[1][r] += acc1[r] * tS;
                    sD[0][r] += acc0[r] * tD;  sD[1][r] += acc1[r] * tD;
                }
                if (ct & 1) {   // head (ch*4 + ct>>1) complete: reduce over 16-lane col group
                    #pragma unroll
                    for (int m = 1; m <= 8; m <<= 1)
                        #pragma unroll
                        for (int t = 0; t < 2; t++)
                            #pragma unroll
                            for (int r = 0; r < 4; r++) {
                                sS[t][r] += __shfl_xor(sS[t][r], m);
                                sD[t][r] += __shfl_xor(sD[t][r], m);
                            }
                    int hd = ch * 4 + (ct >> 1);
                    if (lrow < 8) {
                        int t2 = lrow >> 2, rr = lrow & 3;
                        int row = row0w + t2 * 16 + quad * 4 + rr;
                        if (row < NN) a_src[row * NH + hd] = sel8(sS, t2, rr);
                    } else {
                        int lr = lrow - 8;
                        int t2 = lr >> 2, rr = lr & 3;
                        int row = row0w + t2 * 16 + quad * 4 + rr;
                        if (row < NN) a_dst[row * NH + hd] = sel8(sD, t2, rr);
                    }
                }
            }
        }
    } else {
        // ---- bucket fill: one edge per thread, NT streaming ----
        const long long e = (long long)(b - GEMMB) * 256 + tid;   // < NE by construction
        int dst, src;
        if (i64) {
            dst = (int)__builtin_nontemporal_load((const long long*)ei + e);
            src = (int)__builtin_nontemporal_load((const long long*)ei + NE + e);
        } else {
            dst = __builtin_nontemporal_load(ei + e);
            src = __builtin_nontemporal_load(ei + NE + e);
        }
        unsigned int msk = 0;
        if (f32) {
            const floatx4* dp = (const floatx4*)((const float*)dpm + e * 8);
            floatx4 d0 = __builtin_nontemporal_load(dp);
            floatx4 d1 = __builtin_nontemporal_load(dp + 1);
            #pragma unroll
            for (int j = 0; j < 4; j++) {
                msk |= (d0[j] != 0.f ? 1u : 0u) << j;
                msk |= (d1[j] != 0.f ? 1u : 0u) << (4 + j);
            }
        } else {
            const short4v* dp = (const short4v*)((const unsigned short*)dpm + e * 8);
            short4v d0 = __builtin_nontemporal_load(dp);
            short4v d1 = __builtin_nontemporal_load(dp + 1);
            #pragma unroll
            for (int j = 0; j < 4; j++) {
                msk |= (d0[j] != 0 ? 1u : 0u) << j;
                msk |= (d1[j] != 0 ? 1u : 0u) << (4 + j);
            }
        }
        unsigned int entry = (unsigned int)src | (msk << 16);
        int pos = atomicAdd(&cnt[dst], 1);
        if (pos < cap) {
            __builtin_nontemporal_store(entry, &bucket[((long long)dst << capl2) + pos]);
        } else {
            int op = atomicAdd(ovfcnt, 1);
            if (op < OVFCAP) ovf[op] = make_int2(dst, (int)entry);
        }
    }
}

// ---- K2 v5 (unchanged from R6): lane L owns edge L (cap == 64 == wave size).
//      Upfront phase (full MLP, no serial chain): one coalesced bucket load,
//      TWO contiguous floatx4 a_src loads per lane (all 8 head scores of its
//      edge), 8 exps; signed weights (sign = dropout bit) stored to a per-wave
//      LDS table [head][edge] (padded, conflict-free). Chunk loop is then just:
//      broadcast ds_read of weights + scalar readlane for the h-row base +
//      gated h-gather + MACs — chunks are data-independent and pipeline.
__global__ __launch_bounds__(256) void k_aggr(
        const int* __restrict__ cnt, const int* __restrict__ ovfcnt,
        const unsigned int* __restrict__ bucket, const int2* __restrict__ ovf,
        const float* __restrict__ a_src, const float* __restrict__ a_dst,
        const unsigned short* __restrict__ h, const void* __restrict__ dps,
        const int* __restrict__ flags, const void* __restrict__ bs_,
        void* __restrict__ out, int cap, int capl2) {
    __shared__ float wsh[4 * 8 * 72];      // 4 waves x [8 heads][72 (64+pad)] = 9,216 B
    const int node = blockIdx.x * 4 + (threadIdx.x >> 6);
    const int lane = threadIdx.x & 63;
    if (node >= NN) return;
    const int unode = __builtin_amdgcn_readfirstlane(node);   // wave-uniform -> SGPR
    const int wave = threadIdx.x >> 6;
    const int f32 = flags[0];
    int novf = *ovfcnt; novf = novf > OVFCAP ? OVFCAP : novf;
    int mn = cnt[unode]; mn = mn < cap ? mn : cap;
    const unsigned int* __restrict__ bp = bucket + ((long long)unode << capl2);

    const int hh = lane >> 3;              // head owned by this lane (consumer)
    const int cb = lane * 4;               // channel base within h-row (shorts)
    float* __restrict__ wl = wsh + wave * (8 * 72);

    // ---- upfront: edge L -> lane L; all-head scores with contiguous loads ----
    int lc = lane < mn ? lane : (mn > 0 ? mn - 1 : 0);
    unsigned int ue = bp[lc];                                   // coalesced
    int esrc = (int)(ue & 0xFFFFu);
    floatx4 as0 = *(const floatx4*)(a_src + esrc * NH);         // 8 head scores,
    floatx4 as1 = *(const floatx4*)(a_src + esrc * NH + 4);     // 32 B contiguous
    // a_dst for all heads: wave-uniform (scalar loads)
    const float* adp = a_dst + unode * NH;
    float ad[8];
    #pragma unroll
    for (int k = 0; k < 8; k++) ad[k] = adp[k];

    const bool valid = lane < mn;
    #pragma unroll
    for (int k = 0; k < 8; k++) {
        float al = (k < 4 ? as0[k & 3] : as1[k & 3]) + ad[k];
        float w = __expf(fmaxf(al, 0.2f * al));
        w = valid ? w : 0.f;
        float ws = ((ue >> (16 + k)) & 1u) ? w : -w;            // sign = dropout bit
        wl[k * 72 + lane] = ws;                                 // [head][edge], pad 72
    }
    __asm__ volatile("s_waitcnt lgkmcnt(0)" ::: "memory");      // wave-local LDS ready

    float dn = 0.f;
    float acc0 = 0.f, acc1 = 0.f, acc2 = 0.f, acc3 = 0.f;
    const float* __restrict__ wr = wl + hh * 72;                // consumer weight row

    #pragma unroll
    for (int c = 0; c < 8; c++) {
        if (8 * c < mn) {                  // mn wave-uniform -> scalar branch
            #define CONS(K) { \
                float wv = wr[8 * c + K];                        /* broadcast read */ \
                dn += fabsf(wv); \
                int s##K = __builtin_amdgcn_readlane((int)ue, 8 * c + K) & 0xFFFF; \
                uint2 v = make_uint2(0u, 0u); \
                if (wv > 0.f) v = *(const uint2*)(h + ((long long)s##K << 8) + cb); \
                float p = wv * 2.5f; \
                acc0 = fmaf(p, blo(v.x), acc0); acc1 = fmaf(p, bhi(v.x), acc1); \
                acc2 = fmaf(p, blo(v.y), acc2); acc3 = fmaf(p, bhi(v.y), acc3); }
            CONS(0) CONS(1) CONS(2) CONS(3) CONS(4) CONS(5) CONS(6) CONS(7)
            #undef CONS
        }
    }

    // overflow sweep (novf ~ 0 in practice; correct for any value)
    for (int i = 0; i < novf; i++) {
        int2 tv = ovf[i];
        if (tv.x == node) {
            unsigned int u = (unsigned int)tv.y;
            int src = (int)(u & 0xFFFFu);
            float adh = a_dst[unode * NH + hh];
            float w = __expf(lrelu(a_src[src * NH + hh] + adh));
            dn += w;
            if ((u >> (16 + hh)) & 1u) {
                uint2 hv = *(const uint2*)(h + ((long long)src << 8) + cb);
                float p = w * 2.5f;
                acc0 = fmaf(p, blo(hv.x), acc0); acc1 = fmaf(p, bhi(hv.x), acc1);
                acc2 = fmaf(p, blo(hv.y), acc2); acc3 = fmaf(p, bhi(hv.y), acc3);
            }
        }
    }
    { // self-loop
        float adh = a_dst[unode * NH + hh];
        float wS = __expf(lrelu(a_src[unode * NH + hh] + adh));
        dn += wS;
        float pS = wS * ldf(dps, f32, (long long)unode * NH + hh);
        uint2 hv = *(const uint2*)(h + ((long long)unode << 8) + cb);
        acc0 = fmaf(pS, blo(hv.x), acc0); acc1 = fmaf(pS, bhi(hv.x), acc1);
        acc2 = fmaf(pS, blo(hv.y), acc2); acc3 = fmaf(pS, bhi(hv.y), acc3);
    }
    float inv = 1.0f / dn;
    float b0 = ldf(bs_, f32, cb + 0), b1 = ldf(bs_, f32, cb + 1);
    float b2 = ldf(bs_, f32, cb + 2), b3 = ldf(bs_, f32, cb + 3);
    if (f32) {
        floatx4 o = {acc0 * inv + b0, acc1 * inv + b1, acc2 * inv + b2, acc3 * inv + b3};
        *(floatx4*)((float*)out + (long long)node * HC + cb) = o;
    } else {
        short4v o;
        o[0] = (short)f2bf(acc0 * inv + b0);
        o[1] = (short)f2bf(acc1 * inv + b1);
        o[2] = (short)f2bf(acc2 * inv + b2);
        o[3] = (short)f2bf(acc3 * inv + b3);
        *(short4v*)((unsigned short*)out + (long long)node * HC + cb) = o;
    }
}

extern "C" void kernel_launch(void* const* d_in, const int* in_sizes, int n_in,
                              void* d_out, int out_size, void* d_ws, size_t ws_size,
                              hipStream_t stream) {
    const void* x       = d_in[0];
    const int*  ei      = (const int*)d_in[1];
    const void* dp_mask = d_in[2];
    const void* dp_self = d_in[3];
    const void* W       = d_in[4];
    const void* att_s   = d_in[5];
    const void* att_d   = d_in[6];
    const void* bias    = d_in[7];

    char* w = (char*)d_ws;
    unsigned short* h      = (unsigned short*)(w + 0);             // 25,600,000
    float*          a_src  = (float*)(w + 25600000);               //  1,600,000
    float*          a_dst  = (float*)(w + 27200000);               //  1,600,000
    int*            cnt    = (int*)(w + 28800000);                 //    200,000
    int*            ovfcnt = (int*)(w + 29000000);                 //          4
    int*            flags  = (int*)(w + 29000064);                 //          8
    int2*           ovf    = (int2*)(w + 29000960);                //  1,048,576
    unsigned int*   bucket = (unsigned int*)(w + 30049536);        //  cap*200,000

    // 512 B slack: k_aggr per-lane bucket reads stay within each node's row
    // (clamped), but keep margin anyway.
    long long avail = (long long)ws_size - 30049536LL - 512LL;
    int cap = 64, capl2 = 6;
    while (cap > 4 && (long long)cap * 200000LL > avail) { cap >>= 1; capl2--; }

    // zero cnt + ovfcnt (+flags; flags rewritten by k_front before k_aggr reads)
    hipMemsetAsync(cnt, 0, 200960, stream);
    k_front<<<NBLK1, 256, 0, stream>>>(x, ei, dp_mask, W, att_s, att_d,
                                       flags, h, a_src, a_dst, cnt, ovfcnt, bucket, ovf,
                                       cap, capl2);
    k_aggr<<<NN / 4, 256, 0, stream>>>(cnt, ovfcnt, bucket, ovf, a_src, a_dst, h,
                                       dp_self, flags, bias, d_out, cap, capl2);
}

// Round 8
// 201.187 us; speedup vs baseline: 1.1758x; 1.0006x over previous
//
#include <hip/hip_runtime.h>

#define NN 50000
#define FIN 128
#define HC 256
#define NH 8
#define NE 800000
#define WROW 136        // padded LDS row (shorts); rows 16B-aligned
#define GEMMB 391       // 391*128 rows >= NN; each gemm block does BOTH column halves
#define NBLK1 3516      // 391 gemm + 3125 fill (3125*256 == NE exactly)
#define OVFCAP 131072

typedef __attribute__((ext_vector_type(8))) short short8;
typedef __attribute__((ext_vector_type(4))) short short4v;
typedef __attribute__((ext_vector_type(4))) float floatx4;

__device__ __forceinline__ float bf2f(unsigned short u) {
    union { unsigned int i; float f; } v; v.i = ((unsigned int)u) << 16; return v.f;
}
__device__ __forceinline__ unsigned short f2bf(float f) {
    union { float f; unsigned int i; } v; v.f = f;
    unsigned int r = v.i + 0x7fffu + ((v.i >> 16) & 1u);
    return (unsigned short)(r >> 16);
}
__device__ __forceinline__ float lrelu(float x) { return x > 0.f ? x : 0.2f * x; }
__device__ __forceinline__ float ldf(const void* p, int f32, long long i) {
    return f32 ? ((const float*)p)[i] : bf2f(((const unsigned short*)p)[i]);
}
__device__ __forceinline__ float sel8(const float s[2][4], int t2, int rr) {
    float a0 = t2 ? s[1][0] : s[0][0];
    float a1 = t2 ? s[1][1] : s[0][1];
    float a2 = t2 ? s[1][2] : s[0][2];
    float a3 = t2 ? s[1][3] : s[0][3];
    return (rr == 0) ? a0 : ((rr == 1) ? a1 : ((rr == 2) ? a2 : a3));
}
// bf16 pair unpack from one dword: low short = <<16, high short = mask (no shift)
__device__ __forceinline__ float blo(unsigned int u) {
    union { unsigned int i; float f; } v; v.i = u << 16; return v.f;
}
__device__ __forceinline__ float bhi(unsigned int u) {
    union { unsigned int i; float f; } v; v.i = u & 0xFFFF0000u; return v.f;
}

// ---- K1: blocks < GEMMB: MFMA GEMM + attention scores (unchanged from R7).
//      blocks >= GEMMB: bucket fill, 1 edge/thread, NT streaming; atomic
//      issued BEFORE the mask computation so its latency overlaps the
//      dpm-load wait + mask VALU.
__global__ __launch_bounds__(256) void k_front(
        const void* __restrict__ x, const int* __restrict__ ei,
        const void* __restrict__ dpm, const void* __restrict__ W,
        const void* __restrict__ as_, const void* __restrict__ ad_,
        int* __restrict__ flags, unsigned short* __restrict__ h,
        float* __restrict__ a_src, float* __restrict__ a_dst,
        int* __restrict__ cnt, int* __restrict__ ovfcnt,
        unsigned int* __restrict__ bucket, int2* __restrict__ ovf,
        int cap, int capl2) {
    __shared__ unsigned short lwt[128 * WROW];   // 34,816 B
    __shared__ int s_bad, s_nz;
    const int tid = threadIdx.x;
    const int b = blockIdx.x;

    // dtype probe (local per block; leading words are L2-hot)
    if (tid == 0) { s_bad = 0; s_nz = 0; }
    __syncthreads();
    {
        unsigned int wv = ((const unsigned int*)dpm)[tid];   // fp32 dp_mask words: 0 or 2.5f
        if (wv != 0u && wv != 0x40200000u) atomicAdd(&s_bad, 1);
        if (((const unsigned int*)ei)[2 * tid + 1] != 0u) atomicAdd(&s_nz, 1);
    }
    __syncthreads();
    const int f32 = (s_bad == 0) ? 1 : 0;
    const int i64 = (s_nz == 0) ? 1 : 0;
    if (b == 0 && tid == 0) { flags[0] = f32; flags[1] = i64; }

    if (b < GEMMB) {
        const int lane = tid & 63;
        const int wave = tid >> 6;
        const int lrow = lane & 15;
        const int quad = lane >> 4;
        const int row0w = b * 128 + wave * 32;

        // ---- load x rows once (bf16 fragments in registers for both halves) ----
        short8 a[2][4];
        #pragma unroll
        for (int t = 0; t < 2; t++)
            #pragma unroll
            for (int q = 0; q < 4; q++)
                #pragma unroll
                for (int j = 0; j < 8; j++) a[t][q][j] = 0;

        #pragma unroll
        for (int t = 0; t < 2; t++) {
            int row = row0w + t * 16 + lrow;
            if (row < NN) {
                if (f32) {
                    const float* xp = (const float*)x + (long long)row * FIN + quad * 8;
                    #pragma unroll
                    for (int q = 0; q < 4; q++) {
                        floatx4 u0 = *(const floatx4*)(xp + q * 32);
                        floatx4 u1 = *(const floatx4*)(xp + q * 32 + 4);
                        #pragma unroll
                        for (int j = 0; j < 4; j++) {
                            a[t][q][j]     = (short)f2bf(u0[j]);
                            a[t][q][j + 4] = (short)f2bf(u1[j]);
                        }
                    }
                } else {
                    const unsigned short* xp = (const unsigned short*)x + (long long)row * FIN + quad * 8;
                    #pragma unroll
                    for (int q = 0; q < 4; q++) a[t][q] = *(const short8*)(xp + q * 32);
                }
            }
        }

        #pragma unroll
        for (int ch = 0; ch < 2; ch++) {
            if (ch) __syncthreads();       // all reads of previous half done
            // ---- stage W^T half: two threads per column, 64 k's each; coalesced ----
            {
                const int lcol = tid & 127;
                const int col = ch * 128 + lcol;
                const int k0 = (tid >> 7) * 64;
                if (f32) {
                    const float* wp = (const float*)W + col;
                    for (int k = k0; k < k0 + 64; k++) lwt[lcol * WROW + k] = f2bf(wp[(long long)k * HC]);
                } else {
                    const unsigned short* wp = (const unsigned short*)W + col;
                    for (int k = k0; k < k0 + 64; k++) lwt[lcol * WROW + k] = wp[(long long)k * HC];
                }
            }
            __syncthreads();

            float sS[2][4], sD[2][4];
            #pragma unroll 4
            for (int ct = 0; ct < 8; ct++) {
                if ((ct & 1) == 0) {
                    #pragma unroll
                    for (int t = 0; t < 2; t++)
                        #pragma unroll
                        for (int r = 0; r < 4; r++) { sS[t][r] = 0.f; sD[t][r] = 0.f; }
                }
                floatx4 acc0 = {0.f, 0.f, 0.f, 0.f};
                floatx4 acc1 = {0.f, 0.f, 0.f, 0.f};
                const unsigned short* wp = lwt + (ct * 16 + lrow) * WROW + quad * 8;
                #pragma unroll
                for (int q = 0; q < 4; q++) {
                    short8 bb = *(const short8*)(wp + q * 32);
                    acc0 = __builtin_amdgcn_mfma_f32_16x16x32_bf16(a[0][q], bb, acc0, 0, 0, 0);
                    acc1 = __builtin_amdgcn_mfma_f32_16x16x32_bf16(a[1][q], bb, acc1, 0, 0, 0);
                }
                const int gcol = ch * 128 + ct * 16 + lrow;
                // C/D: col = lane&15, row = quad*4 + reg
                #pragma unroll
                for (int r = 0; r < 4; r++) {
                    int orow = row0w + quad * 4 + r;
                    if (orow < NN) h[(long long)orow * HC + gcol] = f2bf(acc0[r]);
                    int orow1 = orow + 16;
                    if (orow1 < NN) h[(long long)orow1 * HC + gcol] = f2bf(acc1[r]);
                }
                float tS = ldf(as_, f32, gcol);
                float tD = ldf(ad_, f32, gcol);
                #pragma unroll
                for (int r = 0; r < 4; r++) {
                    sS[0][r] += acc0[r] * tS;  sS[1][r] += acc1[r] * tS;
                    sD[0][r] += acc0[r] * tD;  sD[1][r] += acc1[r] * tD;
                }
                if (ct & 1) {   // head (ch*4 + ct>>1) complete: reduce over 16-lane col group
                    #pragma unroll
                    for (int m = 1; m <= 8; m <<= 1)
                        #pragma unroll
                        for (int t = 0; t < 2; t++)
                            #pragma unroll
                            for (int r = 0; r < 4; r++) {
                                sS[t][r] += __shfl_xor(sS[t][r], m);
                                sD[t][r] += __shfl_xor(sD[t][r], m);
                            }
                    int hd = ch * 4 + (ct >> 1);
                    if (lrow < 8) {
                        int t2 = lrow >> 2, rr = lrow & 3;
                        int row = row0w + t2 * 16 + quad * 4 + rr;
                        if (row < NN) a_src[row * NH + hd] = sel8(sS, t2, rr);
                    } else {
                        int lr = lrow - 8;
                        int t2 = lr >> 2, rr = lr & 3;
                        int row = row0w + t2 * 16 + quad * 4 + rr;
                        if (row < NN) a_dst[row * NH + hd] = sel8(sD, t2, rr);
                    }
                }
            }
        }
    } else {
        // ---- bucket fill: one edge per thread, NT streaming, atomic early ----
        const long long e = (long long)(b - GEMMB) * 256 + tid;   // < NE by construction
        int dst, src;
        if (i64) {
            dst = (int)__builtin_nontemporal_load((const long long*)ei + e);
            src = (int)__builtin_nontemporal_load((const long long*)ei + NE + e);
        } else {
            dst = __builtin_nontemporal_load(ei + e);
            src = __builtin_nontemporal_load(ei + NE + e);
        }
        int pos;
        unsigned int msk = 0;
        if (f32) {
            const floatx4* dp = (const floatx4*)((const float*)dpm + e * 8);
            floatx4 d0 = __builtin_nontemporal_load(dp);
            floatx4 d1 = __builtin_nontemporal_load(dp + 1);
            pos = atomicAdd(&cnt[dst], 1);         // in flight during mask VALU
            #pragma unroll
            for (int j = 0; j < 4; j++) {
                msk |= (d0[j] != 0.f ? 1u : 0u) << j;
                msk |= (d1[j] != 0.f ? 1u : 0u) << (4 + j);
            }
        } else {
            const short4v* dp = (const short4v*)((const unsigned short*)dpm + e * 8);
            short4v d0 = __builtin_nontemporal_load(dp);
            short4v d1 = __builtin_nontemporal_load(dp + 1);
            pos = atomicAdd(&cnt[dst], 1);
            #pragma unroll
            for (int j = 0; j < 4; j++) {
                msk |= (d0[j] != 0 ? 1u : 0u) << j;
                msk |= (d1[j] != 0 ? 1u : 0u) << (4 + j);
            }
        }
        unsigned int entry = (unsigned int)src | (msk << 16);
        if (pos < cap) {
            __builtin_nontemporal_store(entry, &bucket[((long long)dst << capl2) + pos]);
        } else {
            int op = atomicAdd(ovfcnt, 1);
            if (op < OVFCAP) ovf[op] = make_int2(dst, (int)entry);
        }
    }
}

// ---- K2 v6: TWO nodes per wave on the v5 structure. Lanes 0-31 are node A's
//      producers (edge l32), lanes 32-63 node B's; weights (sign = dropout)
//      go to per-wave per-node LDS tables [8][68]. Edges 32..63 (rare,
//      Poisson(16)) via a second wave-uniform producer pass. Consumer phase
//      runs A and B CONS groups in one unrolled loop -> two independent
//      gather/MAC chains in flight; upfront random-gather cost amortized
//      over 2 nodes.
__global__ __launch_bounds__(256) void k_aggr(
        const int* __restrict__ cnt, const int* __restrict__ ovfcnt,
        const unsigned int* __restrict__ bucket, const int2* __restrict__ ovf,
        const float* __restrict__ a_src, const float* __restrict__ a_dst,
        const unsigned short* __restrict__ h, const void* __restrict__ dps,
        const int* __restrict__ flags, const void* __restrict__ bs_,
        void* __restrict__ out, int cap, int capl2) {
    __shared__ float wsh[4 * 2 * 8 * 68];      // 4 waves x 2 nodes x [8][68] = 17,408 B
    const int wid = blockIdx.x * 4 + (threadIdx.x >> 6);
    const int lane = threadIdx.x & 63;
    const int nA = wid * 2;
    if (nA >= NN) return;
    const int uA = __builtin_amdgcn_readfirstlane(nA);   // wave-uniform -> SGPR
    const int uB = uA + 1;                               // NN even -> uB < NN
    const int wave = threadIdx.x >> 6;
    const int f32 = flags[0];
    int novf = *ovfcnt; novf = novf > OVFCAP ? OVFCAP : novf;
    int mnA = cnt[uA]; mnA = mnA < cap ? mnA : cap;
    int mnB = cnt[uB]; mnB = mnB < cap ? mnB : cap;
    const unsigned int* __restrict__ bpA = bucket + ((long long)uA << capl2);
    const unsigned int* __restrict__ bpB = bucket + ((long long)uB << capl2);

    const int half = lane >> 5;            // 0 = produce for A, 1 = for B
    const int l32 = lane & 31;
    const int hh = lane >> 3;              // consumer head of this lane
    const int cb = lane * 4;               // channel base within h-row (shorts)

    const int mnH = half ? mnB : mnA;
    const int unH = half ? uB : uA;
    const unsigned int* __restrict__ bpH = half ? bpB : bpA;
    float* __restrict__ wl = wsh + wave * (2 * 8 * 68) + half * (8 * 68);

    // ---- producer pass 1: edge l32 (0..31) of own node ----
    int lc = l32 < mnH ? l32 : (mnH > 0 ? mnH - 1 : 0);
    unsigned int ue = bpH[lc];
    {
        int esrc = (int)(ue & 0xFFFFu);
        floatx4 as0 = *(const floatx4*)(a_src + esrc * NH);
        floatx4 as1 = *(const floatx4*)(a_src + esrc * NH + 4);
        floatx4 ad0 = *(const floatx4*)(a_dst + unH * NH);
        floatx4 ad1 = *(const floatx4*)(a_dst + unH * NH + 4);
        const bool valid = l32 < mnH;
        #pragma unroll
        for (int k = 0; k < 8; k++) {
            float al = (k < 4 ? as0[k & 3] : as1[k & 3]) + (k < 4 ? ad0[k & 3] : ad1[k & 3]);
            float w = __expf(fmaxf(al, 0.2f * al));
            w = valid ? w : 0.f;
            wl[k * 68 + l32] = ((ue >> (16 + k)) & 1u) ? w : -w;   // sign = dropout bit
        }
    }
    // ---- producer pass 2 (rare, wave-uniform): edges 32..63 ----
    unsigned int ue2 = 0u;
    if (mnA > 32 || mnB > 32) {
        int idx2 = 32 + l32;
        int lc2 = idx2 < mnH ? idx2 : (mnH > 0 ? mnH - 1 : 0);
        ue2 = bpH[lc2];
        int esrc = (int)(ue2 & 0xFFFFu);
        floatx4 as0 = *(const floatx4*)(a_src + esrc * NH);
        floatx4 as1 = *(const floatx4*)(a_src + esrc * NH + 4);
        floatx4 ad0 = *(const floatx4*)(a_dst + unH * NH);
        floatx4 ad1 = *(const floatx4*)(a_dst + unH * NH + 4);
        const bool valid = idx2 < mnH;
        #pragma unroll
        for (int k = 0; k < 8; k++) {
            float al = (k < 4 ? as0[k & 3] : as1[k & 3]) + (k < 4 ? ad0[k & 3] : ad1[k & 3]);
            float w = __expf(fmaxf(al, 0.2f * al));
            w = valid ? w : 0.f;
            wl[k * 68 + 32 + l32] = ((ue2 >> (16 + k)) & 1u) ? w : -w;
        }
    }
    __asm__ volatile("s_waitcnt lgkmcnt(0)" ::: "memory");   // wave-local LDS ready

    float dnA = 0.f, dnB = 0.f;
    float aA0 = 0.f, aA1 = 0.f, aA2 = 0.f, aA3 = 0.f;
    float aB0 = 0.f, aB1 = 0.f, aB2 = 0.f, aB3 = 0.f;
    const float* __restrict__ wrA = wsh + wave * (2 * 8 * 68) + hh * 68;
    const float* __restrict__ wrB = wrA + 8 * 68;

    // A edge j source holder: j<32 -> ue@lane j ; j>=32 -> ue2@lane j-32
    // B edge j source holder: j<32 -> ue@lane 32+j ; j>=32 -> ue2@lane j
    #pragma unroll
    for (int c = 0; c < 8; c++) {
        if (8 * c < mnA) {                 // wave-uniform scalar branch
            #define CONSA(K) { \
                float wv = wrA[8 * c + K]; \
                dnA += fabsf(wv); \
                int s = (c < 4 ? __builtin_amdgcn_readlane((int)ue, 8 * c + K) \
                               : __builtin_amdgcn_readlane((int)ue2, 8 * c + K - 32)) & 0xFFFF; \
                uint2 v = make_uint2(0u, 0u); \
                if (wv > 0.f) v = *(const uint2*)(h + ((long long)s << 8) + cb); \
                float p = wv * 2.5f; \
                aA0 = fmaf(p, blo(v.x), aA0); aA1 = fmaf(p, bhi(v.x), aA1); \
                aA2 = fmaf(p, blo(v.y), aA2); aA3 = fmaf(p, bhi(v.y), aA3); }
            CONSA(0) CONSA(1) CONSA(2) CONSA(3) CONSA(4) CONSA(5) CONSA(6) CONSA(7)
            #undef CONSA
        }
        if (8 * c < mnB) {
            #define CONSB(K) { \
                float wv = wrB[8 * c + K]; \
                dnB += fabsf(wv); \
                int s = (c < 4 ? __builtin_amdgcn_readlane((int)ue, 32 + 8 * c + K) \
                               : __builtin_amdgcn_readlane((int)ue2, 8 * c + K)) & 0xFFFF; \
                uint2 v = make_uint2(0u, 0u); \
                if (wv > 0.f) v = *(const uint2*)(h + ((long long)s << 8) + cb); \
                float p = wv * 2.5f; \
                aB0 = fmaf(p, blo(v.x), aB0); aB1 = fmaf(p, bhi(v.x), aB1); \
                aB2 = fmaf(p, blo(v.y), aB2); aB3 = fmaf(p, bhi(v.y), aB3); }
            CONSB(0) CONSB(1) CONSB(2) CONSB(3) CONSB(4) CONSB(5) CONSB(6) CONSB(7)
            #undef CONSB
        }
    }

    // overflow sweep (novf ~ 0 in practice; correct for any value)
    for (int i = 0; i < novf; i++) {
        int2 tv = ovf[i];
        if (tv.x == uA || tv.x == uB) {
            unsigned int u = (unsigned int)tv.y;
            int src = (int)(u & 0xFFFFu);
            float adh = a_dst[tv.x * NH + hh];
            float w = __expf(lrelu(a_src[src * NH + hh] + adh));
            uint2 hv = make_uint2(0u, 0u);
            if ((u >> (16 + hh)) & 1u) hv = *(const uint2*)(h + ((long long)src << 8) + cb);
            float p = w * 2.5f;
            if (tv.x == uA) {
                dnA += w;
                aA0 = fmaf(p, blo(hv.x), aA0); aA1 = fmaf(p, bhi(hv.x), aA1);
                aA2 = fmaf(p, blo(hv.y), aA2); aA3 = fmaf(p, bhi(hv.y), aA3);
            } else {
                dnB += w;
                aB0 = fmaf(p, blo(hv.x), aB0); aB1 = fmaf(p, bhi(hv.x), aB1);
                aB2 = fmaf(p, blo(hv.y), aB2); aB3 = fmaf(p, bhi(hv.y), aB3);
            }
        }
    }
    { // self-loops, both nodes
        float adhA = a_dst[uA * NH + hh], adhB = a_dst[uB * NH + hh];
        float wSA = __expf(lrelu(a_src[uA * NH + hh] + adhA));
        float wSB = __expf(lrelu(a_src[uB * NH + hh] + adhB));
        dnA += wSA; dnB += wSB;
        float pSA = wSA * ldf(dps, f32, (long long)uA * NH + hh);
        float pSB = wSB * ldf(dps, f32, (long long)uB * NH + hh);
        uint2 hvA = *(const uint2*)(h + ((long long)uA << 8) + cb);
        uint2 hvB = *(const uint2*)(h + ((long long)uB << 8) + cb);
        aA0 = fmaf(pSA, blo(hvA.x), aA0); aA1 = fmaf(pSA, bhi(hvA.x), aA1);
        aA2 = fmaf(pSA, blo(hvA.y), aA2); aA3 = fmaf(pSA, bhi(hvA.y), aA3);
        aB0 = fmaf(pSB, blo(hvB.x), aB0); aB1 = fmaf(pSB, bhi(hvB.x), aB1);
        aB2 = fmaf(pSB, blo(hvB.y), aB2); aB3 = fmaf(pSB, bhi(hvB.y), aB3);
    }
    float invA = 1.0f / dnA, invB = 1.0f / dnB;
    float b0 = ldf(bs_, f32, cb + 0), b1 = ldf(bs_, f32, cb + 1);
    float b2 = ldf(bs_, f32, cb + 2), b3 = ldf(bs_, f32, cb + 3);
    if (f32) {
        floatx4 oA = {aA0 * invA + b0, aA1 * invA + b1, aA2 * invA + b2, aA3 * invA + b3};
        floatx4 oB = {aB0 * invB + b0, aB1 * invB + b1, aB2 * invB + b2, aB3 * invB + b3};
        *(floatx4*)((float*)out + (long long)uA * HC + cb) = oA;
        *(floatx4*)((float*)out + (long long)uB * HC + cb) = oB;
    } else {
        short4v oA, oB;
        oA[0] = (short)f2bf(aA0 * invA + b0); oA[1] = (short)f2bf(aA1 * invA + b1);
        oA[2] = (short)f2bf(aA2 * invA + b2); oA[3] = (short)f2bf(aA3 * invA + b3);
        oB[0] = (short)f2bf(aB0 * invB + b0); oB[1] = (short)f2bf(aB1 * invB + b1);
        oB[2] = (short)f2bf(aB2 * invB + b2); oB[3] = (short)f2bf(aB3 * invB + b3);
        *(short4v*)((unsigned short*)out + (long long)uA * HC + cb) = oA;
        *(short4v*)((unsigned short*)out + (long long)uB * HC + cb) = oB;
    }
}

extern "C" void kernel_launch(void* const* d_in, const int* in_sizes, int n_in,
                              void* d_out, int out_size, void* d_ws, size_t ws_size,
                              hipStream_t stream) {
    const void* x       = d_in[0];
    const int*  ei      = (const int*)d_in[1];
    const void* dp_mask = d_in[2];
    const void* dp_self = d_in[3];
    const void* W       = d_in[4];
    const void* att_s   = d_in[5];
    const void* att_d   = d_in[6];
    const void* bias    = d_in[7];

    char* w = (char*)d_ws;
    unsigned short* h      = (unsigned short*)(w + 0);             // 25,600,000
    float*          a_src  = (float*)(w + 25600000);               //  1,600,000
    float*          a_dst  = (float*)(w + 27200000);               //  1,600,000
    int*            cnt    = (int*)(w + 28800000);                 //    200,000
    int*            ovfcnt = (int*)(w + 29000000);                 //          4
    int*            flags  = (int*)(w + 29000064);                 //          8
    int2*           ovf    = (int2*)(w + 29000960);                //  1,048,576
    unsigned int*   bucket = (unsigned int*)(w + 30049536);        //  cap*200,000

    // 512 B slack after bucket region (clamped reads stay in-row; margin only)
    long long avail = (long long)ws_size - 30049536LL - 512LL;
    int cap = 64, capl2 = 6;
    while (cap > 4 && (long long)cap * 200000LL > avail) { cap >>= 1; capl2--; }

    // zero cnt + ovfcnt (+flags; flags rewritten by k_front before k_aggr reads)
    hipMemsetAsync(cnt, 0, 200960, stream);
    k_front<<<NBLK1, 256, 0, stream>>>(x, ei, dp_mask, W, att_s, att_d,
                                       flags, h, a_src, a_dst, cnt, ovfcnt, bucket, ovf,
                                       cap, capl2);
    k_aggr<<<NN / 8, 256, 0, stream>>>(cnt, ovfcnt, bucket, ovf, a_src, a_dst, h,
                                       dp_self, flags, bias, d_out, cap, capl2);
}